// Round 1
// baseline (1197.685 us; speedup 1.0000x reference)
//
#include <hip/hip_runtime.h>
#include <hip/hip_bf16.h>
#include <stdint.h>

#define B_SZ 4096
#define D_SZ 1280
#define L_SZ 16384
#define K_TOP 64
#define C_TARGET 96
#define C_CAP 256

typedef __attribute__((ext_vector_type(8))) short s16x8;
typedef __attribute__((ext_vector_type(4))) float f32x4;

#define GLOAD_LDS16(gp, lp)                                                          \
  __builtin_amdgcn_global_load_lds((const __attribute__((address_space(1))) void*)(gp), \
                                   (__attribute__((address_space(3))) void*)(lp), 16, 0, 0)

static __device__ __forceinline__ unsigned short f2bf(float f) {
  __hip_bfloat16 h = __float2bfloat16(f);
  return *reinterpret_cast<unsigned short*>(&h);
}

// ---------------------------------------------------------------- prep A: bf16(x - pb)
__global__ __launch_bounds__(256) void sae_prep_a(const float* __restrict__ x,
                                                  const float* __restrict__ pb,
                                                  unsigned short* __restrict__ A) {
  const int r = blockIdx.x, t = threadIdx.x;
  const float* xr = x + (size_t)r * D_SZ;
  unsigned short* ar = A + (size_t)r * D_SZ;
  for (int d = t; d < D_SZ; d += 256) ar[d] = f2bf(xr[d] - pb[d]);
}

// ------------------------------------------- prep W: W_encT (f32) + W_bf16T, both [L][D]
__global__ __launch_bounds__(256) void sae_prep_w(const float* __restrict__ W,
                                                  float* __restrict__ WT,
                                                  unsigned short* __restrict__ WbT) {
  __shared__ float tile[64][65];
  const int l0 = blockIdx.x * 64;
  const int d0 = blockIdx.y * 64;
  const int t = threadIdx.x;
  const int c = t & 63, rg = t >> 6;
#pragma unroll
  for (int i = 0; i < 16; ++i) {
    const int row = i * 4 + rg;  // d offset
    tile[row][c] = W[(size_t)(d0 + row) * L_SZ + l0 + c];
  }
  __syncthreads();
#pragma unroll
  for (int i = 0; i < 16; ++i) {
    const int row = i * 4 + rg;          // l offset
    const float v = tile[c][row];        // = W[d0+c][l0+row]
    const size_t o = (size_t)(l0 + row) * D_SZ + d0 + c;
    WT[o] = v;
    WbT[o] = f2bf(v);
  }
}

// ---------------------------------------------------------------- encode GEMM (bf16 MFMA)
// C[m][n] = sum_k A[m][k] * WT[n][k] + lb[n];  A:[B][D] bf16, WT:[L][D] bf16 (B^T form)
__global__ __launch_bounds__(256) void sae_gemm(const unsigned short* __restrict__ A,
                                                const unsigned short* __restrict__ WT,
                                                const float* __restrict__ lb,
                                                float* __restrict__ zpre) {
  __shared__ short As[128 * 32];
  __shared__ short Bs[128 * 32];
  const int t = threadIdx.x;
  const int lane = t & 63, w = t >> 6;
  const int n0 = blockIdx.x * 128, m0 = blockIdx.y * 128;
  const int wm = w >> 1, wn = w & 1;

  f32x4 acc[4][4] = {};

  // staging: each wave, per issue, covers 16 rows x 32 k (4 lanes/row, 16B/lane), LDS linear
  const char* gA = (const char*)(A + (size_t)(m0 + w * 16 + (lane >> 2)) * D_SZ) + (lane & 3) * 16;
  const char* gB = (const char*)(WT + (size_t)(n0 + w * 16 + (lane >> 2)) * D_SZ) + (lane & 3) * 16;
  const size_t rowskip = (size_t)64 * D_SZ * 2;  // +64 rows

  char* lA0 = (char*)As + w * 1024;
  char* lA1 = (char*)As + 4096 + w * 1024;
  char* lB0 = (char*)Bs + w * 1024;
  char* lB1 = (char*)Bs + 4096 + w * 1024;

  const char* paBase = (const char*)As + (wm * 64 + (lane & 15)) * 64 + (lane >> 4) * 16;
  const char* pbBase = (const char*)Bs + (wn * 64 + (lane & 15)) * 64 + (lane >> 4) * 16;

  for (int kt = 0; kt < D_SZ / 32; ++kt) {
    __syncthreads();  // previous compute done; LDS reusable
    GLOAD_LDS16(gA, lA0);
    GLOAD_LDS16(gA + rowskip, lA1);
    GLOAD_LDS16(gB, lB0);
    GLOAD_LDS16(gB + rowskip, lB1);
    gA += 64;
    gB += 64;
    __syncthreads();  // vmcnt drain + barrier

    s16x8 af[4], bg[4];
#pragma unroll
    for (int i = 0; i < 4; ++i) af[i] = *(const s16x8*)(paBase + i * 1024);
#pragma unroll
    for (int j = 0; j < 4; ++j) bg[j] = *(const s16x8*)(pbBase + j * 1024);
#pragma unroll
    for (int i = 0; i < 4; ++i)
#pragma unroll
      for (int j = 0; j < 4; ++j)
        acc[i][j] = __builtin_amdgcn_mfma_f32_16x16x32_bf16(af[i], bg[j], acc[i][j], 0, 0, 0);
  }

  // epilogue: C/D layout col=lane&15, row=(lane>>4)*4+reg  [guide m89]
  const int cl = lane & 15, rg = lane >> 4;
#pragma unroll
  for (int i = 0; i < 4; ++i)
#pragma unroll
    for (int j = 0; j < 4; ++j) {
      const int cc = wn * 64 + j * 16 + cl;
      const float bias = lb[n0 + cc];
      const size_t base = (size_t)(m0 + wm * 64 + i * 16 + rg * 4) * L_SZ + n0 + cc;
#pragma unroll
      for (int tt = 0; tt < 4; ++tt) zpre[base + (size_t)tt * L_SZ] = acc[i][j][tt] + bias;
    }
}

// ---------------------------------------------------------------- radix-select helper
__device__ void radix_pick(unsigned* hist, unsigned* suf, int* sh_b, unsigned* sh_above,
                           int target, int t) {
  if (t == 0) *sh_b = -1;
  unsigned p = hist[4 * t] + hist[4 * t + 1] + hist[4 * t + 2] + hist[4 * t + 3];
  suf[t] = p;
  for (int off = 1; off < 256; off <<= 1) {
    __syncthreads();
    unsigned v = (t + off < 256) ? suf[t + off] : 0u;
    __syncthreads();
    suf[t] += v;
  }
  __syncthreads();
  const unsigned shi = (t + 1 < 256) ? suf[t + 1] : 0u;
  unsigned S = shi;
  int best = -1;
#pragma unroll
  for (int i = 3; i >= 0; --i) {  // bins from top: first hit = local max bin
    S += hist[4 * t + i];
    if (S >= (unsigned)target) { best = 4 * t + i; break; }
  }
  if (best >= 0) atomicMax(sh_b, best);
  __syncthreads();
  const int b = *sh_b;
  if ((b >> 2) == t) {
    unsigned above = shi;
    for (int i = 3; i > (b & 3); --i) above += hist[4 * t + i];
    *sh_above = above;
  }
  __syncthreads();
}

// ------------------------------------------- top-C candidates per row by bf16 zpre value
__global__ __launch_bounds__(256) void sae_topc(const float* __restrict__ zpre,
                                                int* __restrict__ cand_idx,
                                                int* __restrict__ cand_cnt) {
  __shared__ unsigned keys[L_SZ];  // 64 KB
  __shared__ unsigned hist[1024];
  __shared__ unsigned suf[256];
  __shared__ int sh_b0, sh_b1, sh_cnt;
  __shared__ unsigned sh_above;
  const int r = blockIdx.x, t = threadIdx.x;
  const float* zr = zpre + (size_t)r * L_SZ;

  for (int i = t; i < L_SZ / 4; i += 256) {
    float4 v = ((const float4*)zr)[i];
    unsigned u0 = __float_as_uint(v.x), u1 = __float_as_uint(v.y);
    unsigned u2 = __float_as_uint(v.z), u3 = __float_as_uint(v.w);
    keys[4 * i + 0] = (u0 & 0x80000000u) ? ~u0 : (u0 | 0x80000000u);
    keys[4 * i + 1] = (u1 & 0x80000000u) ? ~u1 : (u1 | 0x80000000u);
    keys[4 * i + 2] = (u2 & 0x80000000u) ? ~u2 : (u2 | 0x80000000u);
    keys[4 * i + 3] = (u3 & 0x80000000u) ? ~u3 : (u3 | 0x80000000u);
  }
  for (int i = t; i < 1024; i += 256) hist[i] = 0;
  if (t == 0) sh_cnt = 0;
  __syncthreads();
  for (int i = t; i < L_SZ; i += 256) atomicAdd(&hist[keys[i] >> 22], 1u);
  __syncthreads();
  radix_pick(hist, suf, &sh_b0, &sh_above, C_TARGET, t);
  const int b0 = sh_b0;
  const int target2 = C_TARGET - (int)sh_above;
  __syncthreads();
  for (int i = t; i < 1024; i += 256) hist[i] = 0;
  __syncthreads();
  for (int i = t; i < L_SZ; i += 256) {
    const unsigned k = keys[i];
    if ((int)(k >> 22) == b0) atomicAdd(&hist[(k >> 12) & 1023u], 1u);
  }
  __syncthreads();
  radix_pick(hist, suf, &sh_b1, &sh_above, target2, t);
  const unsigned cutoff = (((unsigned)b0 << 10) | (unsigned)sh_b1) << 12;
  __syncthreads();
  for (int i = t; i < L_SZ; i += 256) {
    if (keys[i] >= cutoff) {
      const int s = atomicAdd(&sh_cnt, 1);
      if (s < C_CAP) cand_idx[(size_t)r * C_CAP + s] = i;
    }
  }
  __syncthreads();
  if (t == 0) cand_cnt[r] = sh_cnt < C_CAP ? sh_cnt : C_CAP;
}

// ------------------------------------------- exact f64 recompute of candidate dots
__global__ __launch_bounds__(256) void sae_refine(const float* __restrict__ x,
                                                  const float* __restrict__ pb,
                                                  const float* __restrict__ WT,
                                                  const float* __restrict__ lb,
                                                  const int* __restrict__ cand_idx,
                                                  const int* __restrict__ cand_cnt,
                                                  double* __restrict__ cand_val) {
  __shared__ double xs[D_SZ];
  const int r = blockIdx.x, t = threadIdx.x;
  const int lane = t & 63, w = t >> 6;
  const float* xr = x + (size_t)r * D_SZ;
  for (int d = t; d < D_SZ; d += 256) xs[d] = (double)xr[d] - (double)pb[d];
  __syncthreads();
  const int nc = cand_cnt[r];
  for (int ci = w; ci < nc; ci += 4) {
    const int c = cand_idx[(size_t)r * C_CAP + ci];
    const float* wc = WT + (size_t)c * D_SZ;
    double acc = 0.0;
    for (int d = lane; d < D_SZ; d += 64) acc += xs[d] * (double)wc[d];
    for (int off = 32; off > 0; off >>= 1) acc += __shfl_down(acc, off);
    if (lane == 0) cand_val[(size_t)r * C_CAP + ci] = acc + (double)lb[c];
  }
}

// ------------------------------------------- exact top-64 among candidates (rank by value)
__global__ __launch_bounds__(256) void sae_select64(const int* __restrict__ cand_idx,
                                                    const int* __restrict__ cand_cnt,
                                                    const double* __restrict__ cand_val,
                                                    int* __restrict__ top_idx,
                                                    float* __restrict__ top_val) {
  __shared__ double vals[C_CAP];
  __shared__ int idxs[C_CAP];
  const int r = blockIdx.x, t = threadIdx.x;
  const int nc = cand_cnt[r];
  if (t < nc) {
    vals[t] = cand_val[(size_t)r * C_CAP + t];
    idxs[t] = cand_idx[(size_t)r * C_CAP + t];
  }
  __syncthreads();
  if (t < nc) {
    const double v = vals[t];
    const int id = idxs[t];
    int rank = 0;
    for (int j = 0; j < nc; ++j) {
      const double vj = vals[j];
      if (vj > v || (vj == v && idxs[j] < id)) ++rank;
    }
    if (rank < K_TOP) {
      top_idx[(size_t)r * K_TOP + rank] = id;
      float f = (float)v;
      if (f < 0.f) f = 0.f;  // relu on top-k values, like reference
      top_val[(size_t)r * K_TOP + rank] = f;
    }
  }
}

// ------------------------------------------- sparse decode: xhat = pb + sum v_k * W_dec[idx_k]
__global__ __launch_bounds__(256) void sae_decode(const int* __restrict__ top_idx,
                                                  const float* __restrict__ top_val,
                                                  const float* __restrict__ Wd,
                                                  const float* __restrict__ pb,
                                                  float* __restrict__ xhat) {
  __shared__ int id_s[K_TOP];
  __shared__ float v_s[K_TOP];
  const int r = blockIdx.x, t = threadIdx.x;
  if (t < K_TOP) {
    id_s[t] = top_idx[(size_t)r * K_TOP + t];
    v_s[t] = top_val[(size_t)r * K_TOP + t];
  }
  __syncthreads();
  for (int d = t; d < D_SZ; d += 256) {
    double acc = (double)pb[d];
#pragma unroll 8
    for (int k = 0; k < K_TOP; ++k) acc += (double)v_s[k] * (double)Wd[(size_t)id_s[k] * D_SZ + d];
    xhat[(size_t)r * D_SZ + d] = (float)acc;
  }
}

// ------------------------------------------- scatter rows 0..4063 (region already zeroed)
__global__ void sae_scatterA(const int* __restrict__ top_idx, const float* __restrict__ top_val,
                             float* __restrict__ z) {
  const int r = blockIdx.x;  // 0..4063
  const int t = threadIdx.x; // 0..63
  const int id = top_idx[(size_t)r * K_TOP + t];
  const float v = top_val[(size_t)r * K_TOP + t];
  z[(size_t)r * L_SZ + id] = v;
}

// ---------------------- tail: rows 4064..4095 overlap the list scratch; single block handles
__global__ __launch_bounds__(256) void sae_scatterB(const int* __restrict__ top_idx,
                                                    const float* __restrict__ top_val,
                                                    float* __restrict__ z) {
  __shared__ int ids[32 * K_TOP];
  __shared__ float vs[32 * K_TOP];
  const int t = threadIdx.x;
  for (int i = t; i < 32 * K_TOP; i += 256) {
    ids[i] = top_idx[(size_t)4064 * K_TOP + i];
    vs[i] = top_val[(size_t)4064 * K_TOP + i];
  }
  __syncthreads();
  float4* zz = (float4*)(z + (size_t)4064 * L_SZ);
  for (int i = t; i < 32 * L_SZ / 4; i += 256) zz[i] = make_float4(0.f, 0.f, 0.f, 0.f);
  __syncthreads();
  for (int i = t; i < 32 * K_TOP; i += 256) {
    const int rr = 4064 + i / K_TOP;
    z[(size_t)rr * L_SZ + ids[i]] = vs[i];
  }
}

extern "C" void kernel_launch(void* const* d_in, const int* in_sizes, int n_in,
                              void* d_out, int out_size, void* d_ws, size_t ws_size,
                              hipStream_t stream) {
  const float* x  = (const float*)d_in[0];
  const float* pb = (const float*)d_in[1];
  const float* We = (const float*)d_in[2];
  const float* lb = (const float*)d_in[3];
  const float* Wd = (const float*)d_in[4];

  float* zpre = (float*)d_out;
  float* z    = zpre + (size_t)B_SZ * L_SZ;
  float* xhat = z + (size_t)B_SZ * L_SZ;

  // Scratch lives inside the z output region (exactly 256 MiB), dead until the final phase.
  char* zb = (char*)z;
  unsigned short* A_bf   = (unsigned short*)(zb);                        // 10 MiB
  unsigned short* WT_bf  = (unsigned short*)(zb + ((size_t)16 << 20));   // 40 MiB
  float*          WT_f32 = (float*)(zb + ((size_t)64 << 20));            // 80 MiB
  int*            c_idx  = (int*)(zb + ((size_t)160 << 20));             // 4 MiB
  int*            c_cnt  = (int*)(zb + ((size_t)164 << 20));             // 16 KiB
  double*         c_val  = (double*)(zb + ((size_t)168 << 20));          // 8 MiB
  int*            t_idx  = (int*)(zb + ((size_t)254 << 20));             // 1 MiB (tail)
  float*          t_val  = (float*)(zb + ((size_t)255 << 20));           // 1 MiB (tail)

  sae_prep_a<<<B_SZ, 256, 0, stream>>>(x, pb, A_bf);
  sae_prep_w<<<dim3(L_SZ / 64, D_SZ / 64), 256, 0, stream>>>(We, WT_f32, WT_bf);
  sae_gemm<<<dim3(L_SZ / 128, B_SZ / 128), 256, 0, stream>>>(A_bf, WT_bf, lb, zpre);
  sae_topc<<<B_SZ, 256, 0, stream>>>(zpre, c_idx, c_cnt);
  sae_refine<<<B_SZ, 256, 0, stream>>>(x, pb, WT_f32, lb, c_idx, c_cnt, c_val);
  sae_select64<<<B_SZ, 256, 0, stream>>>(c_idx, c_cnt, c_val, t_idx, t_val);
  sae_decode<<<B_SZ, 256, 0, stream>>>(t_idx, t_val, Wd, pb, xhat);
  // zero z rows 0..4063 (254 MiB); tail rows 4064..4095 hold the lists, handled by scatterB
  hipMemsetAsync(z, 0, (size_t)4064 * L_SZ * sizeof(float), stream);
  sae_scatterA<<<4064, K_TOP, 0, stream>>>(t_idx, t_val, z);
  sae_scatterB<<<1, 256, 0, stream>>>(t_idx, t_val, z);
}

// Round 2
// 1076.809 us; speedup vs baseline: 1.1123x; 1.1123x over previous
//
#include <hip/hip_runtime.h>
#include <hip/hip_bf16.h>
#include <stdint.h>

#define B_SZ 4096
#define D_SZ 1280
#define L_SZ 16384
#define K_TOP 64
#define C_TARGET 96
#define C_CAP 256

typedef __attribute__((ext_vector_type(8))) short s16x8;
typedef __attribute__((ext_vector_type(4))) float f32x4;

#define GLOAD_LDS16(gp, lp)                                                          \
  __builtin_amdgcn_global_load_lds((const __attribute__((address_space(1))) void*)(gp), \
                                   (__attribute__((address_space(3))) void*)(lp), 16, 0, 0)

static __device__ __forceinline__ unsigned short f2bf(float f) {
  __hip_bfloat16 h = __float2bfloat16(f);
  return *reinterpret_cast<unsigned short*>(&h);
}

// ------------------------------- prep A: bf16(x - pb) for GEMM + f32(x - pb) for refine
__global__ __launch_bounds__(256) void sae_prep_a(const float* __restrict__ x,
                                                  const float* __restrict__ pb,
                                                  unsigned short* __restrict__ A,
                                                  float* __restrict__ xs) {
  const int r = blockIdx.x, t = threadIdx.x;
  const float* xr = x + (size_t)r * D_SZ;
  unsigned short* ar = A + (size_t)r * D_SZ;
  float* sr = xs + (size_t)r * D_SZ;
  for (int d = t; d < D_SZ; d += 256) {
    const float v = xr[d] - pb[d];
    ar[d] = f2bf(v);
    sr[d] = v;
  }
}

// ------------------------------------------- prep W: W_encT (f32) + W_bf16T, both [L][D]
__global__ __launch_bounds__(256) void sae_prep_w(const float* __restrict__ W,
                                                  float* __restrict__ WT,
                                                  unsigned short* __restrict__ WbT) {
  __shared__ float tile[64][65];
  const int l0 = blockIdx.x * 64;
  const int d0 = blockIdx.y * 64;
  const int t = threadIdx.x;
  const int c = t & 63, rg = t >> 6;
#pragma unroll
  for (int i = 0; i < 16; ++i) {
    const int row = i * 4 + rg;  // d offset
    tile[row][c] = W[(size_t)(d0 + row) * L_SZ + l0 + c];
  }
  __syncthreads();
#pragma unroll
  for (int i = 0; i < 16; ++i) {
    const int row = i * 4 + rg;          // l offset
    const float v = tile[c][row];        // = W[d0+c][l0+row]
    const size_t o = (size_t)(l0 + row) * D_SZ + d0 + c;
    WT[o] = v;
    WbT[o] = f2bf(v);
  }
}

// ---------------------------------------------------------------- encode GEMM (bf16 MFMA)
// C[m][n] = sum_k A[m][k] * WT[n][k] + lb[n];  A:[B][D] bf16, WT:[L][D] bf16 (B^T form)
__global__ __launch_bounds__(256) void sae_gemm(const unsigned short* __restrict__ A,
                                                const unsigned short* __restrict__ WT,
                                                const float* __restrict__ lb,
                                                float* __restrict__ zpre) {
  __shared__ short As[128 * 32];
  __shared__ short Bs[128 * 32];
  const int t = threadIdx.x;
  const int lane = t & 63, w = t >> 6;
  const int n0 = blockIdx.x * 128, m0 = blockIdx.y * 128;
  const int wm = w >> 1, wn = w & 1;

  f32x4 acc[4][4] = {};

  const char* gA = (const char*)(A + (size_t)(m0 + w * 16 + (lane >> 2)) * D_SZ) + (lane & 3) * 16;
  const char* gB = (const char*)(WT + (size_t)(n0 + w * 16 + (lane >> 2)) * D_SZ) + (lane & 3) * 16;
  const size_t rowskip = (size_t)64 * D_SZ * 2;  // +64 rows

  char* lA0 = (char*)As + w * 1024;
  char* lA1 = (char*)As + 4096 + w * 1024;
  char* lB0 = (char*)Bs + w * 1024;
  char* lB1 = (char*)Bs + 4096 + w * 1024;

  const char* paBase = (const char*)As + (wm * 64 + (lane & 15)) * 64 + (lane >> 4) * 16;
  const char* pbBase = (const char*)Bs + (wn * 64 + (lane & 15)) * 64 + (lane >> 4) * 16;

  for (int kt = 0; kt < D_SZ / 32; ++kt) {
    __syncthreads();
    GLOAD_LDS16(gA, lA0);
    GLOAD_LDS16(gA + rowskip, lA1);
    GLOAD_LDS16(gB, lB0);
    GLOAD_LDS16(gB + rowskip, lB1);
    gA += 64;
    gB += 64;
    __syncthreads();

    s16x8 af[4], bg[4];
#pragma unroll
    for (int i = 0; i < 4; ++i) af[i] = *(const s16x8*)(paBase + i * 1024);
#pragma unroll
    for (int j = 0; j < 4; ++j) bg[j] = *(const s16x8*)(pbBase + j * 1024);
#pragma unroll
    for (int i = 0; i < 4; ++i)
#pragma unroll
      for (int j = 0; j < 4; ++j)
        acc[i][j] = __builtin_amdgcn_mfma_f32_16x16x32_bf16(af[i], bg[j], acc[i][j], 0, 0, 0);
  }

  const int cl = lane & 15, rg = lane >> 4;
#pragma unroll
  for (int i = 0; i < 4; ++i)
#pragma unroll
    for (int j = 0; j < 4; ++j) {
      const int cc = wn * 64 + j * 16 + cl;
      const float bias = lb[n0 + cc];
      const size_t base = (size_t)(m0 + wm * 64 + i * 16 + rg * 4) * L_SZ + n0 + cc;
#pragma unroll
      for (int tt = 0; tt < 4; ++tt) zpre[base + (size_t)tt * L_SZ] = acc[i][j][tt] + bias;
    }
}

// ---------------------------------------------------------------- radix-select helper
__device__ void radix_pick(unsigned* hist, unsigned* suf, int* sh_b, unsigned* sh_above,
                           int target, int t) {
  if (t == 0) *sh_b = -1;
  unsigned p = hist[4 * t] + hist[4 * t + 1] + hist[4 * t + 2] + hist[4 * t + 3];
  suf[t] = p;
  for (int off = 1; off < 256; off <<= 1) {
    __syncthreads();
    unsigned v = (t + off < 256) ? suf[t + off] : 0u;
    __syncthreads();
    suf[t] += v;
  }
  __syncthreads();
  const unsigned shi = (t + 1 < 256) ? suf[t + 1] : 0u;
  unsigned S = shi;
  int best = -1;
#pragma unroll
  for (int i = 3; i >= 0; --i) {
    S += hist[4 * t + i];
    if (S >= (unsigned)target) { best = 4 * t + i; break; }
  }
  if (best >= 0) atomicMax(sh_b, best);
  __syncthreads();
  const int b = *sh_b;
  if ((b >> 2) == t) {
    unsigned above = shi;
    for (int i = 3; i > (b & 3); --i) above += hist[4 * t + i];
    *sh_above = above;
  }
  __syncthreads();
}

// ------------------------------------------- top-C candidates per row by bf16 zpre value
__global__ __launch_bounds__(256) void sae_topc(const float* __restrict__ zpre,
                                                int* __restrict__ cand_idx,
                                                int* __restrict__ cand_cnt) {
  __shared__ unsigned keys[L_SZ];  // 64 KB
  __shared__ unsigned hist[1024];
  __shared__ unsigned suf[256];
  __shared__ int sh_b0, sh_b1, sh_cnt;
  __shared__ unsigned sh_above;
  const int r = blockIdx.x, t = threadIdx.x;
  const float* zr = zpre + (size_t)r * L_SZ;

  for (int i = t; i < L_SZ / 4; i += 256) {
    float4 v = ((const float4*)zr)[i];
    unsigned u0 = __float_as_uint(v.x), u1 = __float_as_uint(v.y);
    unsigned u2 = __float_as_uint(v.z), u3 = __float_as_uint(v.w);
    keys[4 * i + 0] = (u0 & 0x80000000u) ? ~u0 : (u0 | 0x80000000u);
    keys[4 * i + 1] = (u1 & 0x80000000u) ? ~u1 : (u1 | 0x80000000u);
    keys[4 * i + 2] = (u2 & 0x80000000u) ? ~u2 : (u2 | 0x80000000u);
    keys[4 * i + 3] = (u3 & 0x80000000u) ? ~u3 : (u3 | 0x80000000u);
  }
  for (int i = t; i < 1024; i += 256) hist[i] = 0;
  if (t == 0) sh_cnt = 0;
  __syncthreads();
  for (int i = t; i < L_SZ; i += 256) atomicAdd(&hist[keys[i] >> 22], 1u);
  __syncthreads();
  radix_pick(hist, suf, &sh_b0, &sh_above, C_TARGET, t);
  const int b0 = sh_b0;
  const int target2 = C_TARGET - (int)sh_above;
  __syncthreads();
  for (int i = t; i < 1024; i += 256) hist[i] = 0;
  __syncthreads();
  for (int i = t; i < L_SZ; i += 256) {
    const unsigned k = keys[i];
    if ((int)(k >> 22) == b0) atomicAdd(&hist[(k >> 12) & 1023u], 1u);
  }
  __syncthreads();
  radix_pick(hist, suf, &sh_b1, &sh_above, target2, t);
  const unsigned cutoff = (((unsigned)b0 << 10) | (unsigned)sh_b1) << 12;
  __syncthreads();
  for (int i = t; i < L_SZ; i += 256) {
    if (keys[i] >= cutoff) {
      const int s = atomicAdd(&sh_cnt, 1);
      if (s < C_CAP) cand_idx[(size_t)r * C_CAP + s] = i;
    }
  }
  __syncthreads();
  if (t == 0) cand_cnt[r] = sh_cnt < C_CAP ? sh_cnt : C_CAP;
}

// ------------------------------------------- bucket candidates by latent: count
__global__ __launch_bounds__(256) void sae_bucket_count(const int* __restrict__ cand_idx,
                                                        const int* __restrict__ cand_cnt,
                                                        int* __restrict__ counts) {
  const int r = blockIdx.x, t = threadIdx.x;
  if (t < cand_cnt[r]) atomicAdd(&counts[cand_idx[(size_t)r * C_CAP + t]], 1);
}

// ------------------------------------------- exclusive scan over 16384 counts (1 block)
__global__ __launch_bounds__(256) void sae_scan(const int* __restrict__ counts,
                                                int* __restrict__ offsets,
                                                int* __restrict__ cursor) {
  __shared__ int part[256];
  const int t = threadIdx.x;
  int s = 0;
  for (int i = 0; i < 64; ++i) s += counts[t * 64 + i];
  part[t] = s;
  __syncthreads();
  int excl = 0;
  for (int j = 0; j < t; ++j) excl += part[j];
  int run = excl;
  for (int i = 0; i < 64; ++i) {
    const int idx = t * 64 + i;
    offsets[idx] = run;
    cursor[idx] = run;
    run += counts[idx];
  }
}

// ------------------------------------------- bucket fill: entries[pos] = (row<<8)|slot
__global__ __launch_bounds__(256) void sae_bucket_fill(const int* __restrict__ cand_idx,
                                                       const int* __restrict__ cand_cnt,
                                                       int* __restrict__ cursor,
                                                       int* __restrict__ entries) {
  const int r = blockIdx.x, t = threadIdx.x;
  if (t < cand_cnt[r]) {
    const int l = cand_idx[(size_t)r * C_CAP + t];
    const int pos = atomicAdd(&cursor[l], 1);
    entries[pos] = (r << 8) | t;
  }
}

// ------------------------------------------- latent-major exact f64 recompute
// One block per latent: W_encT row (contiguous, streamed once) in LDS; gather xs rows
// (20 MB hot set -> LLC/L2) per bucketed candidate. Each wave handles one candidate dot.
__global__ __launch_bounds__(256) void sae_refine_lm(const float* __restrict__ xs,
                                                     const float* __restrict__ WT,
                                                     const float* __restrict__ lb,
                                                     const int* __restrict__ counts,
                                                     const int* __restrict__ offsets,
                                                     const int* __restrict__ entries,
                                                     double* __restrict__ cand_val) {
  __shared__ float wl[D_SZ];
  const int l = blockIdx.x;
  const int t = threadIdx.x, lane = t & 63, w = t >> 6;
  const float* wc = WT + (size_t)l * D_SZ;
  for (int d = t; d < D_SZ; d += 256) wl[d] = wc[d];
  __syncthreads();
  const int n = counts[l], base = offsets[l];
  const double bias = (double)lb[l];
  for (int e = w; e < n; e += 4) {
    const int ent = entries[base + e];
    const int r = ent >> 8, s = ent & 255;
    const float* xr = xs + (size_t)r * D_SZ;
    double acc = 0.0;
#pragma unroll 5
    for (int d = lane; d < D_SZ; d += 64) acc += (double)xr[d] * (double)wl[d];
#pragma unroll
    for (int off = 32; off > 0; off >>= 1) acc += __shfl_down(acc, off);
    if (lane == 0) cand_val[(size_t)r * C_CAP + s] = acc + bias;
  }
}

// ------------------------------------------- exact top-64 among candidates (rank by value)
__global__ __launch_bounds__(256) void sae_select64(const int* __restrict__ cand_idx,
                                                    const int* __restrict__ cand_cnt,
                                                    const double* __restrict__ cand_val,
                                                    int* __restrict__ top_idx,
                                                    float* __restrict__ top_val) {
  __shared__ double vals[C_CAP];
  __shared__ int idxs[C_CAP];
  const int r = blockIdx.x, t = threadIdx.x;
  const int nc = cand_cnt[r];
  if (t < nc) {
    vals[t] = cand_val[(size_t)r * C_CAP + t];
    idxs[t] = cand_idx[(size_t)r * C_CAP + t];
  }
  __syncthreads();
  if (t < nc) {
    const double v = vals[t];
    const int id = idxs[t];
    int rank = 0;
    for (int j = 0; j < nc; ++j) {
      const double vj = vals[j];
      if (vj > v || (vj == v && idxs[j] < id)) ++rank;
    }
    if (rank < K_TOP) {
      top_idx[(size_t)r * K_TOP + rank] = id;
      float f = (float)v;
      if (f < 0.f) f = 0.f;
      top_val[(size_t)r * K_TOP + rank] = f;
    }
  }
}

// ------------------------------------------- sparse decode: xhat = pb + sum v_k * W_dec[idx_k]
__global__ __launch_bounds__(256) void sae_decode(const int* __restrict__ top_idx,
                                                  const float* __restrict__ top_val,
                                                  const float* __restrict__ Wd,
                                                  const float* __restrict__ pb,
                                                  float* __restrict__ xhat) {
  __shared__ int id_s[K_TOP];
  __shared__ float v_s[K_TOP];
  const int r = blockIdx.x, t = threadIdx.x;
  if (t < K_TOP) {
    id_s[t] = top_idx[(size_t)r * K_TOP + t];
    v_s[t] = top_val[(size_t)r * K_TOP + t];
  }
  __syncthreads();
  for (int d = t; d < D_SZ; d += 256) {
    double acc = (double)pb[d];
#pragma unroll 8
    for (int k = 0; k < K_TOP; ++k) acc += (double)v_s[k] * (double)Wd[(size_t)id_s[k] * D_SZ + d];
    xhat[(size_t)r * D_SZ + d] = (float)acc;
  }
}

// ------------------------------------------- scatter rows 0..4063 (region already zeroed)
__global__ void sae_scatterA(const int* __restrict__ top_idx, const float* __restrict__ top_val,
                             float* __restrict__ z) {
  const int r = blockIdx.x;
  const int t = threadIdx.x;
  const int id = top_idx[(size_t)r * K_TOP + t];
  const float v = top_val[(size_t)r * K_TOP + t];
  z[(size_t)r * L_SZ + id] = v;
}

// ---------------------- tail: rows 4064..4095 overlap the list scratch; single block handles
__global__ __launch_bounds__(256) void sae_scatterB(const int* __restrict__ top_idx,
                                                    const float* __restrict__ top_val,
                                                    float* __restrict__ z) {
  __shared__ int ids[32 * K_TOP];
  __shared__ float vs[32 * K_TOP];
  const int t = threadIdx.x;
  for (int i = t; i < 32 * K_TOP; i += 256) {
    ids[i] = top_idx[(size_t)4064 * K_TOP + i];
    vs[i] = top_val[(size_t)4064 * K_TOP + i];
  }
  __syncthreads();
  float4* zz = (float4*)(z + (size_t)4064 * L_SZ);
  for (int i = t; i < 32 * L_SZ / 4; i += 256) zz[i] = make_float4(0.f, 0.f, 0.f, 0.f);
  __syncthreads();
  for (int i = t; i < 32 * K_TOP; i += 256) {
    const int rr = 4064 + i / K_TOP;
    z[(size_t)rr * L_SZ + ids[i]] = vs[i];
  }
}

extern "C" void kernel_launch(void* const* d_in, const int* in_sizes, int n_in,
                              void* d_out, int out_size, void* d_ws, size_t ws_size,
                              hipStream_t stream) {
  const float* x  = (const float*)d_in[0];
  const float* pb = (const float*)d_in[1];
  const float* We = (const float*)d_in[2];
  const float* lb = (const float*)d_in[3];
  const float* Wd = (const float*)d_in[4];

  float* zpre = (float*)d_out;
  float* z    = zpre + (size_t)B_SZ * L_SZ;
  float* xhat = z + (size_t)B_SZ * L_SZ;

  // Scratch lives inside the z output region (256 MiB), dead until the final phase.
  char* zb = (char*)z;
  unsigned short* A_bf   = (unsigned short*)(zb);                        // 10 MiB
  unsigned short* WT_bf  = (unsigned short*)(zb + ((size_t)16 << 20));   // 40 MiB
  float*          WT_f32 = (float*)(zb + ((size_t)64 << 20));            // 80 MiB
  int*            c_idx  = (int*)(zb + ((size_t)160 << 20));             // 4 MiB
  int*            c_cnt  = (int*)(zb + ((size_t)164 << 20));             // 16 KiB
  double*         c_val  = (double*)(zb + ((size_t)168 << 20));          // 8 MiB
  float*          xs_f32 = (float*)(zb + ((size_t)176 << 20));           // 20 MiB
  int*            bk_cnt = (int*)(zb + ((size_t)200 << 20));             // 64 KiB
  int*            bk_off = (int*)(zb + ((size_t)201 << 20));             // 64 KiB
  int*            bk_cur = (int*)(zb + ((size_t)202 << 20));             // 64 KiB
  int*            bk_ent = (int*)(zb + ((size_t)208 << 20));             // 4 MiB
  int*            t_idx  = (int*)(zb + ((size_t)254 << 20));             // 1 MiB (tail)
  float*          t_val  = (float*)(zb + ((size_t)255 << 20));           // 1 MiB (tail)

  sae_prep_a<<<B_SZ, 256, 0, stream>>>(x, pb, A_bf, xs_f32);
  sae_prep_w<<<dim3(L_SZ / 64, D_SZ / 64), 256, 0, stream>>>(We, WT_f32, WT_bf);
  sae_gemm<<<dim3(L_SZ / 128, B_SZ / 128), 256, 0, stream>>>(A_bf, WT_bf, lb, zpre);
  sae_topc<<<B_SZ, 256, 0, stream>>>(zpre, c_idx, c_cnt);
  hipMemsetAsync(bk_cnt, 0, (size_t)L_SZ * sizeof(int), stream);
  sae_bucket_count<<<B_SZ, 256, 0, stream>>>(c_idx, c_cnt, bk_cnt);
  sae_scan<<<1, 256, 0, stream>>>(bk_cnt, bk_off, bk_cur);
  sae_bucket_fill<<<B_SZ, 256, 0, stream>>>(c_idx, c_cnt, bk_cur, bk_ent);
  sae_refine_lm<<<L_SZ, 256, 0, stream>>>(xs_f32, WT_f32, lb, bk_cnt, bk_off, bk_ent, c_val);
  sae_select64<<<B_SZ, 256, 0, stream>>>(c_idx, c_cnt, c_val, t_idx, t_val);
  sae_decode<<<B_SZ, 256, 0, stream>>>(t_idx, t_val, Wd, pb, xhat);
  hipMemsetAsync(z, 0, (size_t)4064 * L_SZ * sizeof(float), stream);
  sae_scatterA<<<4064, K_TOP, 0, stream>>>(t_idx, t_val, z);
  sae_scatterB<<<1, 256, 0, stream>>>(t_idx, t_val, z);
}

// Round 3
// 1047.611 us; speedup vs baseline: 1.1433x; 1.0279x over previous
//
#include <hip/hip_runtime.h>
#include <hip/hip_bf16.h>
#include <stdint.h>

#define B_SZ 4096
#define D_SZ 1280
#define L_SZ 16384
#define K_TOP 64
#define C_TARGET 80
#define C_CAP 256

typedef __attribute__((ext_vector_type(8))) short s16x8;
typedef __attribute__((ext_vector_type(4))) float f32x4;

#define GLOAD_LDS16(gp, lp)                                                          \
  __builtin_amdgcn_global_load_lds((const __attribute__((address_space(1))) void*)(gp), \
                                   (__attribute__((address_space(3))) void*)(lp), 16, 0, 0)

static __device__ __forceinline__ unsigned short f2bf(float f) {
  __hip_bfloat16 h = __float2bfloat16(f);
  return *reinterpret_cast<unsigned short*>(&h);
}

// ------------------------------- prep A: bf16(x - pb) for GEMM + f32(x - pb) for refine
__global__ __launch_bounds__(256) void sae_prep_a(const float* __restrict__ x,
                                                  const float* __restrict__ pb,
                                                  unsigned short* __restrict__ A,
                                                  float* __restrict__ xs) {
  const int r = blockIdx.x, t = threadIdx.x;
  const float* xr = x + (size_t)r * D_SZ;
  unsigned short* ar = A + (size_t)r * D_SZ;
  float* sr = xs + (size_t)r * D_SZ;
  for (int d = t; d < D_SZ; d += 256) {
    const float v = xr[d] - pb[d];
    ar[d] = f2bf(v);
    sr[d] = v;
  }
}

// ------------------------------------------- prep W: W_encT (f32) + W_bf16T, both [L][D]
__global__ __launch_bounds__(256) void sae_prep_w(const float* __restrict__ W,
                                                  float* __restrict__ WT,
                                                  unsigned short* __restrict__ WbT) {
  __shared__ float tile[64][65];
  const int l0 = blockIdx.x * 64;
  const int d0 = blockIdx.y * 64;
  const int t = threadIdx.x;
  const int c = t & 63, rg = t >> 6;
#pragma unroll
  for (int i = 0; i < 16; ++i) {
    const int row = i * 4 + rg;  // d offset
    tile[row][c] = W[(size_t)(d0 + row) * L_SZ + l0 + c];
  }
  __syncthreads();
#pragma unroll
  for (int i = 0; i < 16; ++i) {
    const int row = i * 4 + rg;          // l offset
    const float v = tile[c][row];        // = W[d0+c][l0+row]
    const size_t o = (size_t)(l0 + row) * D_SZ + d0 + c;
    WT[o] = v;
    WbT[o] = f2bf(v);
  }
}

// ---------------------------------------------------------------- encode GEMM (bf16 MFMA)
// C[m][n] = sum_k A[m][k] * WT[n][k] + lb[n];  A:[B][D] bf16, WT:[L][D] bf16 (B^T form)
// 1-D grid of 4096 blocks, XCD-swizzled so each XCD keeps one B-panel L2-resident.
__global__ __launch_bounds__(256) void sae_gemm(const unsigned short* __restrict__ A,
                                                const unsigned short* __restrict__ WT,
                                                const float* __restrict__ lb,
                                                float* __restrict__ zpre) {
  __shared__ short As[128 * 32];
  __shared__ short Bs[128 * 32];
  const int t = threadIdx.x;
  const int lane = t & 63, w = t >> 6;
  // XCD swizzle: 4096 blocks, 8 XCDs, 512 contiguous wg per XCD; tm fastest within XCD
  const int bid = blockIdx.x;
  const int wg = (bid & 7) * 512 + (bid >> 3);
  const int m0 = (wg & 31) * 128;   // 32 M-tiles
  const int n0 = (wg >> 5) * 128;   // 128 N-tiles
  const int wm = w >> 1, wn = w & 1;

  f32x4 acc[4][4] = {};

  const char* gA = (const char*)(A + (size_t)(m0 + w * 16 + (lane >> 2)) * D_SZ) + (lane & 3) * 16;
  const char* gB = (const char*)(WT + (size_t)(n0 + w * 16 + (lane >> 2)) * D_SZ) + (lane & 3) * 16;
  const size_t rowskip = (size_t)64 * D_SZ * 2;  // +64 rows

  char* lA0 = (char*)As + w * 1024;
  char* lA1 = (char*)As + 4096 + w * 1024;
  char* lB0 = (char*)Bs + w * 1024;
  char* lB1 = (char*)Bs + 4096 + w * 1024;

  const char* paBase = (const char*)As + (wm * 64 + (lane & 15)) * 64 + (lane >> 4) * 16;
  const char* pbBase = (const char*)Bs + (wn * 64 + (lane & 15)) * 64 + (lane >> 4) * 16;

  for (int kt = 0; kt < D_SZ / 32; ++kt) {
    __syncthreads();
    GLOAD_LDS16(gA, lA0);
    GLOAD_LDS16(gA + rowskip, lA1);
    GLOAD_LDS16(gB, lB0);
    GLOAD_LDS16(gB + rowskip, lB1);
    gA += 64;
    gB += 64;
    __syncthreads();

    s16x8 af[4], bg[4];
#pragma unroll
    for (int i = 0; i < 4; ++i) af[i] = *(const s16x8*)(paBase + i * 1024);
#pragma unroll
    for (int j = 0; j < 4; ++j) bg[j] = *(const s16x8*)(pbBase + j * 1024);
#pragma unroll
    for (int i = 0; i < 4; ++i)
#pragma unroll
      for (int j = 0; j < 4; ++j)
        acc[i][j] = __builtin_amdgcn_mfma_f32_16x16x32_bf16(af[i], bg[j], acc[i][j], 0, 0, 0);
  }

  const int cl = lane & 15, rg = lane >> 4;
#pragma unroll
  for (int i = 0; i < 4; ++i)
#pragma unroll
    for (int j = 0; j < 4; ++j) {
      const int cc = wn * 64 + j * 16 + cl;
      const float bias = lb[n0 + cc];
      const size_t base = (size_t)(m0 + wm * 64 + i * 16 + rg * 4) * L_SZ + n0 + cc;
#pragma unroll
      for (int tt = 0; tt < 4; ++tt) zpre[base + (size_t)tt * L_SZ] = acc[i][j][tt] + bias;
    }
}

// ---------------------------------------------------------------- radix-select helper
__device__ void radix_pick(unsigned* hist, unsigned* suf, int* sh_b, unsigned* sh_above,
                           int target, int t) {
  if (t == 0) *sh_b = -1;
  unsigned p = hist[4 * t] + hist[4 * t + 1] + hist[4 * t + 2] + hist[4 * t + 3];
  suf[t] = p;
  for (int off = 1; off < 256; off <<= 1) {
    __syncthreads();
    unsigned v = (t + off < 256) ? suf[t + off] : 0u;
    __syncthreads();
    suf[t] += v;
  }
  __syncthreads();
  const unsigned shi = (t + 1 < 256) ? suf[t + 1] : 0u;
  unsigned S = shi;
  int best = -1;
#pragma unroll
  for (int i = 3; i >= 0; --i) {
    S += hist[4 * t + i];
    if (S >= (unsigned)target) { best = 4 * t + i; break; }
  }
  if (best >= 0) atomicMax(sh_b, best);
  __syncthreads();
  const int b = *sh_b;
  if ((b >> 2) == t) {
    unsigned above = shi;
    for (int i = 3; i > (b & 3); --i) above += hist[4 * t + i];
    *sh_above = above;
  }
  __syncthreads();
}

// ------------------------------------------- top-C candidates per row by bf16 zpre value
__global__ __launch_bounds__(256) void sae_topc(const float* __restrict__ zpre,
                                                int* __restrict__ cand_idx,
                                                int* __restrict__ cand_cnt) {
  __shared__ unsigned keys[L_SZ];  // 64 KB
  __shared__ unsigned hist[1024];
  __shared__ unsigned suf[256];
  __shared__ int sh_b0, sh_b1, sh_cnt;
  __shared__ unsigned sh_above;
  const int r = blockIdx.x, t = threadIdx.x;
  const float* zr = zpre + (size_t)r * L_SZ;

  for (int i = t; i < L_SZ / 4; i += 256) {
    float4 v = ((const float4*)zr)[i];
    unsigned u0 = __float_as_uint(v.x), u1 = __float_as_uint(v.y);
    unsigned u2 = __float_as_uint(v.z), u3 = __float_as_uint(v.w);
    keys[4 * i + 0] = (u0 & 0x80000000u) ? ~u0 : (u0 | 0x80000000u);
    keys[4 * i + 1] = (u1 & 0x80000000u) ? ~u1 : (u1 | 0x80000000u);
    keys[4 * i + 2] = (u2 & 0x80000000u) ? ~u2 : (u2 | 0x80000000u);
    keys[4 * i + 3] = (u3 & 0x80000000u) ? ~u3 : (u3 | 0x80000000u);
  }
  for (int i = t; i < 1024; i += 256) hist[i] = 0;
  if (t == 0) sh_cnt = 0;
  __syncthreads();
  for (int i = t; i < L_SZ; i += 256) atomicAdd(&hist[keys[i] >> 22], 1u);
  __syncthreads();
  radix_pick(hist, suf, &sh_b0, &sh_above, C_TARGET, t);
  const int b0 = sh_b0;
  const int target2 = C_TARGET - (int)sh_above;
  __syncthreads();
  for (int i = t; i < 1024; i += 256) hist[i] = 0;
  __syncthreads();
  for (int i = t; i < L_SZ; i += 256) {
    const unsigned k = keys[i];
    if ((int)(k >> 22) == b0) atomicAdd(&hist[(k >> 12) & 1023u], 1u);
  }
  __syncthreads();
  radix_pick(hist, suf, &sh_b1, &sh_above, target2, t);
  const unsigned cutoff = (((unsigned)b0 << 10) | (unsigned)sh_b1) << 12;
  __syncthreads();
  for (int i = t; i < L_SZ; i += 256) {
    if (keys[i] >= cutoff) {
      const int s = atomicAdd(&sh_cnt, 1);
      if (s < C_CAP) cand_idx[(size_t)r * C_CAP + s] = i;
    }
  }
  __syncthreads();
  if (t == 0) cand_cnt[r] = sh_cnt < C_CAP ? sh_cnt : C_CAP;
}

// ------------------------------------------- bucket candidates by latent: count
__global__ __launch_bounds__(256) void sae_bucket_count(const int* __restrict__ cand_idx,
                                                        const int* __restrict__ cand_cnt,
                                                        int* __restrict__ counts) {
  const int r = blockIdx.x, t = threadIdx.x;
  if (t < cand_cnt[r]) atomicAdd(&counts[cand_idx[(size_t)r * C_CAP + t]], 1);
}

// ------------------------------------------- exclusive scan over 16384 counts (1 block)
__global__ __launch_bounds__(256) void sae_scan(const int* __restrict__ counts,
                                                int* __restrict__ offsets,
                                                int* __restrict__ cursor) {
  __shared__ int part[256];
  const int t = threadIdx.x;
  int s = 0;
  for (int i = 0; i < 64; ++i) s += counts[t * 64 + i];
  part[t] = s;
  __syncthreads();
  int excl = 0;
  for (int j = 0; j < t; ++j) excl += part[j];
  int run = excl;
  for (int i = 0; i < 64; ++i) {
    const int idx = t * 64 + i;
    offsets[idx] = run;
    cursor[idx] = run;
    run += counts[idx];
  }
}

// ------------------------------------------- bucket fill: entries[pos] = (row<<8)|slot
__global__ __launch_bounds__(256) void sae_bucket_fill(const int* __restrict__ cand_idx,
                                                       const int* __restrict__ cand_cnt,
                                                       int* __restrict__ cursor,
                                                       int* __restrict__ entries) {
  const int r = blockIdx.x, t = threadIdx.x;
  if (t < cand_cnt[r]) {
    const int l = cand_idx[(size_t)r * C_CAP + t];
    const int pos = atomicAdd(&cursor[l], 1);
    entries[pos] = (r << 8) | t;
  }
}

// ------------------------------------------- latent-major exact f64 recompute
__global__ __launch_bounds__(256) void sae_refine_lm(const float* __restrict__ xs,
                                                     const float* __restrict__ WT,
                                                     const float* __restrict__ lb,
                                                     const int* __restrict__ counts,
                                                     const int* __restrict__ offsets,
                                                     const int* __restrict__ entries,
                                                     double* __restrict__ cand_val) {
  __shared__ float4 wl[D_SZ / 4];
  const int l = blockIdx.x;
  const int t = threadIdx.x, lane = t & 63, w = t >> 6;
  const float4* wc = (const float4*)(WT + (size_t)l * D_SZ);
  for (int d = t; d < D_SZ / 4; d += 256) wl[d] = wc[d];
  __syncthreads();
  const int n = counts[l], base = offsets[l];
  const double bias = (double)lb[l];
  for (int e = w; e < n; e += 4) {
    const int ent = entries[base + e];
    const int r = ent >> 8, s = ent & 255;
    const float4* xr = (const float4*)(xs + (size_t)r * D_SZ);
    double acc = 0.0;
#pragma unroll
    for (int i = 0; i < 5; ++i) {
      const float4 xv = xr[lane + 64 * i];
      const float4 wv = wl[lane + 64 * i];
      acc += (double)xv.x * (double)wv.x + (double)xv.y * (double)wv.y +
             (double)xv.z * (double)wv.z + (double)xv.w * (double)wv.w;
    }
#pragma unroll
    for (int off = 32; off > 0; off >>= 1) acc += __shfl_down(acc, off);
    if (lane == 0) cand_val[(size_t)r * C_CAP + s] = acc + bias;
  }
}

// ------------------------------------------- exact top-64 among candidates (rank by value)
__global__ __launch_bounds__(256) void sae_select64(const int* __restrict__ cand_idx,
                                                    const int* __restrict__ cand_cnt,
                                                    const double* __restrict__ cand_val,
                                                    int* __restrict__ top_idx,
                                                    float* __restrict__ top_val) {
  __shared__ double vals[C_CAP];
  __shared__ int idxs[C_CAP];
  const int r = blockIdx.x, t = threadIdx.x;
  const int nc = cand_cnt[r];
  if (t < nc) {
    vals[t] = cand_val[(size_t)r * C_CAP + t];
    idxs[t] = cand_idx[(size_t)r * C_CAP + t];
  }
  __syncthreads();
  if (t < nc) {
    const double v = vals[t];
    const int id = idxs[t];
    int rank = 0;
    for (int j = 0; j < nc; ++j) {
      const double vj = vals[j];
      if (vj > v || (vj == v && idxs[j] < id)) ++rank;
    }
    if (rank < K_TOP) {
      top_idx[(size_t)r * K_TOP + rank] = id;
      float f = (float)v;
      if (f < 0.f) f = 0.f;
      top_val[(size_t)r * K_TOP + rank] = f;
    }
  }
}

// ------------------------------------------- dense z row write (zeros + 64 values), 1 blk/row
__global__ __launch_bounds__(256) void sae_zwrite(const int* __restrict__ top_idx,
                                                  const float* __restrict__ top_val,
                                                  float* __restrict__ z) {
  __shared__ int id_s[K_TOP];
  __shared__ float v_s[K_TOP];
  const int r = blockIdx.x, t = threadIdx.x;
  if (t < K_TOP) {
    id_s[t] = top_idx[(size_t)r * K_TOP + t];
    v_s[t] = top_val[(size_t)r * K_TOP + t];
  }
  __syncthreads();
  float4* zr = (float4*)(z + (size_t)r * L_SZ);
#pragma unroll
  for (int i = 0; i < L_SZ / 4 / 256; ++i) zr[t + 256 * i] = make_float4(0.f, 0.f, 0.f, 0.f);
  __syncthreads();
  if (t < K_TOP) z[(size_t)r * L_SZ + id_s[t]] = v_s[t];
}

// ------------------------------------------- sparse decode (float4, 320 thr = 1 slot each)
__global__ __launch_bounds__(320) void sae_decode(const int* __restrict__ top_idx,
                                                  const float* __restrict__ top_val,
                                                  const float* __restrict__ Wd,
                                                  const float* __restrict__ pb,
                                                  float* __restrict__ xhat) {
  __shared__ int id_s[K_TOP];
  __shared__ float v_s[K_TOP];
  const int r = blockIdx.x, t = threadIdx.x;
  if (t < K_TOP) {
    id_s[t] = top_idx[(size_t)r * K_TOP + t];
    v_s[t] = top_val[(size_t)r * K_TOP + t];
  }
  __syncthreads();
  float4 acc = ((const float4*)pb)[t];
#pragma unroll 8
  for (int k = 0; k < K_TOP; ++k) {
    const float4 wv = ((const float4*)(Wd + (size_t)id_s[k] * D_SZ))[t];
    const float vk = v_s[k];
    acc.x += vk * wv.x;
    acc.y += vk * wv.y;
    acc.z += vk * wv.z;
    acc.w += vk * wv.w;
  }
  ((float4*)(xhat + (size_t)r * D_SZ))[t] = acc;
}

// ------------------------------------------- fallback scatter (ws too small): as R2
__global__ void sae_scatterA(const int* __restrict__ top_idx, const float* __restrict__ top_val,
                             float* __restrict__ z) {
  const int r = blockIdx.x;
  const int t = threadIdx.x;
  const int id = top_idx[(size_t)r * K_TOP + t];
  const float v = top_val[(size_t)r * K_TOP + t];
  z[(size_t)r * L_SZ + id] = v;
}

__global__ __launch_bounds__(256) void sae_scatterB(const int* __restrict__ top_idx,
                                                    const float* __restrict__ top_val,
                                                    float* __restrict__ z) {
  __shared__ int ids[32 * K_TOP];
  __shared__ float vs[32 * K_TOP];
  const int t = threadIdx.x;
  for (int i = t; i < 32 * K_TOP; i += 256) {
    ids[i] = top_idx[(size_t)4064 * K_TOP + i];
    vs[i] = top_val[(size_t)4064 * K_TOP + i];
  }
  __syncthreads();
  float4* zz = (float4*)(z + (size_t)4064 * L_SZ);
  for (int i = t; i < 32 * L_SZ / 4; i += 256) zz[i] = make_float4(0.f, 0.f, 0.f, 0.f);
  __syncthreads();
  for (int i = t; i < 32 * K_TOP; i += 256) {
    const int rr = 4064 + i / K_TOP;
    z[(size_t)rr * L_SZ + ids[i]] = vs[i];
  }
}

extern "C" void kernel_launch(void* const* d_in, const int* in_sizes, int n_in,
                              void* d_out, int out_size, void* d_ws, size_t ws_size,
                              hipStream_t stream) {
  const float* x  = (const float*)d_in[0];
  const float* pb = (const float*)d_in[1];
  const float* We = (const float*)d_in[2];
  const float* lb = (const float*)d_in[3];
  const float* Wd = (const float*)d_in[4];

  float* zpre = (float*)d_out;
  float* z    = zpre + (size_t)B_SZ * L_SZ;
  float* xhat = z + (size_t)B_SZ * L_SZ;

  // Scratch lives inside the z output region (256 MiB), dead before z is materialized.
  char* zb = (char*)z;
  unsigned short* A_bf   = (unsigned short*)(zb);                        // 10 MiB
  unsigned short* WT_bf  = (unsigned short*)(zb + ((size_t)16 << 20));   // 40 MiB
  float*          WT_f32 = (float*)(zb + ((size_t)64 << 20));            // 80 MiB
  int*            c_idx  = (int*)(zb + ((size_t)160 << 20));             // 4 MiB
  int*            c_cnt  = (int*)(zb + ((size_t)164 << 20));             // 16 KiB
  double*         c_val  = (double*)(zb + ((size_t)168 << 20));          // 8 MiB
  float*          xs_f32 = (float*)(zb + ((size_t)176 << 20));           // 20 MiB
  int*            bk_cnt = (int*)(zb + ((size_t)200 << 20));             // 64 KiB
  int*            bk_off = (int*)(zb + ((size_t)201 << 20));             // 64 KiB
  int*            bk_cur = (int*)(zb + ((size_t)202 << 20));             // 64 KiB
  int*            bk_ent = (int*)(zb + ((size_t)208 << 20));             // 4 MiB

  const bool use_ws = ws_size >= ((size_t)4 << 20);
  int*   t_idx = use_ws ? (int*)d_ws : (int*)(zb + ((size_t)254 << 20));
  float* t_val = use_ws ? (float*)((char*)d_ws + ((size_t)2 << 20))
                        : (float*)(zb + ((size_t)255 << 20));

  sae_prep_a<<<B_SZ, 256, 0, stream>>>(x, pb, A_bf, xs_f32);
  sae_prep_w<<<dim3(L_SZ / 64, D_SZ / 64), 256, 0, stream>>>(We, WT_f32, WT_bf);
  sae_gemm<<<4096, 256, 0, stream>>>(A_bf, WT_bf, lb, zpre);
  sae_topc<<<B_SZ, 256, 0, stream>>>(zpre, c_idx, c_cnt);
  hipMemsetAsync(bk_cnt, 0, (size_t)L_SZ * sizeof(int), stream);
  sae_bucket_count<<<B_SZ, 256, 0, stream>>>(c_idx, c_cnt, bk_cnt);
  sae_scan<<<1, 256, 0, stream>>>(bk_cnt, bk_off, bk_cur);
  sae_bucket_fill<<<B_SZ, 256, 0, stream>>>(c_idx, c_cnt, bk_cur, bk_ent);
  sae_refine_lm<<<L_SZ, 256, 0, stream>>>(xs_f32, WT_f32, lb, bk_cnt, bk_off, bk_ent, c_val);
  sae_select64<<<B_SZ, 256, 0, stream>>>(c_idx, c_cnt, c_val, t_idx, t_val);
  sae_decode<<<B_SZ, 320, 0, stream>>>(t_idx, t_val, Wd, pb, xhat);
  if (use_ws) {
    sae_zwrite<<<B_SZ, 256, 0, stream>>>(t_idx, t_val, z);
  } else {
    hipMemsetAsync(z, 0, (size_t)4064 * L_SZ * sizeof(float), stream);
    sae_scatterA<<<4064, K_TOP, 0, stream>>>(t_idx, t_val, z);
    sae_scatterB<<<1, 256, 0, stream>>>(t_idx, t_val, z);
  }
}

// Round 4
// 928.701 us; speedup vs baseline: 1.2896x; 1.1280x over previous
//
#include <hip/hip_runtime.h>
#include <hip/hip_bf16.h>
#include <stdint.h>

#define B_SZ 4096
#define D_SZ 1280
#define L_SZ 16384
#define K_TOP 64
#define C_TARGET 80
#define C_CAP 256

typedef __attribute__((ext_vector_type(8))) short s16x8;
typedef __attribute__((ext_vector_type(4))) float f32x4;

#define GLOAD_LDS16(gp, lp)                                                          \
  __builtin_amdgcn_global_load_lds((const __attribute__((address_space(1))) void*)(gp), \
                                   (__attribute__((address_space(3))) void*)(lp), 16, 0, 0)

static __device__ __forceinline__ unsigned short f2bf(float f) {
  __hip_bfloat16 h = __float2bfloat16(f);
  return *reinterpret_cast<unsigned short*>(&h);
}
static __device__ __forceinline__ float bf2f(unsigned short u) {
  return __uint_as_float((unsigned)u << 16);
}

// ------------------------------- prep A: bf16(x - pb) for GEMM + f32(x - pb) for refine
__global__ __launch_bounds__(256) void sae_prep_a(const float* __restrict__ x,
                                                  const float* __restrict__ pb,
                                                  unsigned short* __restrict__ A,
                                                  float* __restrict__ xs) {
  const int r = blockIdx.x, t = threadIdx.x;
  const float* xr = x + (size_t)r * D_SZ;
  unsigned short* ar = A + (size_t)r * D_SZ;
  float* sr = xs + (size_t)r * D_SZ;
  for (int d = t; d < D_SZ; d += 256) {
    const float v = xr[d] - pb[d];
    ar[d] = f2bf(v);
    sr[d] = v;
  }
}

// ------------------------------------------- prep W: W_encT (f32) + W_bf16T, both [L][D]
__global__ __launch_bounds__(256) void sae_prep_w(const float* __restrict__ W,
                                                  float* __restrict__ WT,
                                                  unsigned short* __restrict__ WbT) {
  __shared__ float tile[64][65];
  const int l0 = blockIdx.x * 64;
  const int d0 = blockIdx.y * 64;
  const int t = threadIdx.x;
  const int c = t & 63, rg = t >> 6;
#pragma unroll
  for (int i = 0; i < 16; ++i) {
    const int row = i * 4 + rg;  // d offset
    tile[row][c] = W[(size_t)(d0 + row) * L_SZ + l0 + c];
  }
  __syncthreads();
#pragma unroll
  for (int i = 0; i < 16; ++i) {
    const int row = i * 4 + rg;          // l offset
    const float v = tile[c][row];        // = W[d0+c][l0+row]
    const size_t o = (size_t)(l0 + row) * D_SZ + d0 + c;
    WT[o] = v;
    WbT[o] = f2bf(v);
  }
}

// ------------------------------------------- prep Wd: bf16 copy of W_dec (halves decode gather)
__global__ __launch_bounds__(256) void sae_prep_wd(const float* __restrict__ Wd,
                                                   unsigned short* __restrict__ Wdb) {
  const int n4 = L_SZ * D_SZ / 4;
  for (int i = blockIdx.x * 256 + threadIdx.x; i < n4; i += gridDim.x * 256) {
    const float4 v = ((const float4*)Wd)[i];
    ushort4 o;
    o.x = f2bf(v.x); o.y = f2bf(v.y); o.z = f2bf(v.z); o.w = f2bf(v.w);
    ((ushort4*)Wdb)[i] = o;
  }
}

// ---------------------------------------------------------------- encode GEMM, 256x256 8-phase
// C[m][n] = sum_k A[m][k]*WT[n][k] + lb[n]; A:[4096][1280] bf16, WT:[16384][1280] bf16.
// BM=BN=256, BK=64, 8 waves (2M x 4N), LDS 128KB (2 dbuf x 2 half x 128x64 x A,B).
// LDS swizzle: lin ^= ((lin>>9)&7)<<4 (both-sides: inverse-swz global src + swz ds_read).
#define SWZ(lin) ((lin) ^ ((((lin) >> 9) & 7) << 4))
#define A_LDS 0
#define B_LDS 65536
#define KBYTES (D_SZ * 2)

#define PH_MID()                                          \
  __builtin_amdgcn_s_barrier();                           \
  asm volatile("s_waitcnt lgkmcnt(0)" ::: "memory");      \
  __builtin_amdgcn_sched_barrier(0);                      \
  __builtin_amdgcn_s_setprio(1)

#define PH_END()                                          \
  __builtin_amdgcn_s_setprio(0);                          \
  __builtin_amdgcn_s_barrier();                           \
  __builtin_amdgcn_sched_barrier(0)

__global__ __launch_bounds__(512, 2) void sae_gemm(const unsigned short* __restrict__ A,
                                                   const unsigned short* __restrict__ WT,
                                                   const float* __restrict__ lb,
                                                   float* __restrict__ zpre) {
  __shared__ short lds[65536];  // 128 KiB
  char* ldsc = (char*)lds;
  const int t = threadIdx.x, lane = t & 63, w = t >> 6;
  const int wr = w >> 2, wc = w & 3, w2 = w * 2;

  // XCD-aware swizzle: 1024 blocks = 8 XCD x 128; per XCD 4x4 supertiles
  const int bid = blockIdx.x;
  const int xcd = bid & 7, i2 = bid >> 3;
  const int b2 = i2 >> 4, inner = i2 & 15;
  const int mt = (b2 & 3) * 4 + (inner & 3);
  const int nt = xcd * 8 + (b2 >> 2) * 4 + (inner >> 2);
  const int m0 = mt * 256, n0 = nt * 256;

  f32x4 acc[8][4] = {};

  // stage one half-tile (128 rows x 64 k) of operand into LDS; 2 gload_lds per wave
  auto STAGE = [&](const unsigned short* op, int rowbase, int ldsop, int buf, int half, int tile) {
#pragma unroll
    for (int s = 0; s < 2; ++s) {
      const int o = (w2 + s) * 1024 + lane * 16;           // linear LDS offset in half-tile
      const int r = o >> 7;                                 // row 0..127
      const int cb = (o & 127) ^ (((o >> 9) & 7) << 4);     // inverse-swizzled col byte
      const char* g = (const char*)op + (size_t)(rowbase + half * 128 + r) * KBYTES +
                      tile * 128 + cb;
      char* l = ldsc + ldsop + buf * 32768 + half * 16384 + (w2 + s) * 1024;  // wave-uniform
      GLOAD_LDS16(g, l);
    }
  };
  // A fragments for quadrant q: af[i2*2+kk]
  auto LDA = [&](s16x8* af, int buf, int q) {
#pragma unroll
    for (int i = 0; i < 2; ++i)
#pragma unroll
      for (int kk = 0; kk < 2; ++kk) {
        const int r = (q * 2 + i) * 16 + (lane & 15);
        int lin = r * 128 + kk * 64 + ((lane >> 4) * 16);
        lin = SWZ(lin);
        af[i * 2 + kk] = *(const s16x8*)(ldsc + A_LDS + buf * 32768 + wr * 16384 + lin);
      }
  };
  // B fragments (all 4 n-frags x 2 kk): bg[j*2+kk]
  auto LDB = [&](s16x8* bg, int buf) {
#pragma unroll
    for (int j = 0; j < 4; ++j)
#pragma unroll
      for (int kk = 0; kk < 2; ++kk) {
        const int nloc = wc * 64 + j * 16 + (lane & 15);
        const int half = nloc >> 7, r = nloc & 127;
        int lin = r * 128 + kk * 64 + ((lane >> 4) * 16);
        lin = SWZ(lin);
        bg[j * 2 + kk] = *(const s16x8*)(ldsc + B_LDS + buf * 32768 + half * 16384 + lin);
      }
  };
  auto MM = [&](s16x8* af, s16x8* bg, int q) {
#pragma unroll
    for (int i = 0; i < 2; ++i)
#pragma unroll
      for (int j = 0; j < 4; ++j)
#pragma unroll
        for (int kk = 0; kk < 2; ++kk)
          acc[q * 2 + i][j] =
              __builtin_amdgcn_mfma_f32_16x16x32_bf16(af[i * 2 + kk], bg[j * 2 + kk],
                                                      acc[q * 2 + i][j], 0, 0, 0);
  };

  // prologue: tile0 -> buf0 (B then A), tile1.B -> buf1
  STAGE(WT, n0, B_LDS, 0, 0, 0); STAGE(WT, n0, B_LDS, 0, 1, 0);
  STAGE(A, m0, A_LDS, 0, 0, 0);  STAGE(A, m0, A_LDS, 0, 1, 0);
  STAGE(WT, n0, B_LDS, 1, 0, 1); STAGE(WT, n0, B_LDS, 1, 1, 1);
  asm volatile("s_waitcnt vmcnt(4)" ::: "memory");
  __builtin_amdgcn_s_barrier();
  __builtin_amdgcn_sched_barrier(0);

  const int NI = D_SZ / 128;  // 10 iterations, 2 K-tiles each
  for (int i = 0; i < NI; ++i) {
    const bool last = (i == NI - 1);
    s16x8 af[4], bg[8];
    // ph0: compute buf0.q0; stage buf1.A (tile 2i+1)
    LDB(bg, 0); LDA(af, 0, 0);
    STAGE(A, m0, A_LDS, 1, 0, 2 * i + 1); STAGE(A, m0, A_LDS, 1, 1, 2 * i + 1);
    PH_MID(); MM(af, bg, 0); PH_END();
    // ph1: stage buf0.B-lo (tile 2i+2)
    LDA(af, 0, 1);
    if (!last) STAGE(WT, n0, B_LDS, 0, 0, 2 * i + 2);
    PH_MID(); MM(af, bg, 1); PH_END();
    // ph2: stage buf0.B-hi
    LDA(af, 0, 2);
    if (!last) STAGE(WT, n0, B_LDS, 0, 1, 2 * i + 2);
    PH_MID(); MM(af, bg, 2); PH_END();
    // ph3: close K-tile 2i; counted vmcnt ensures buf1 (tile 2i+1) landed
    LDA(af, 0, 3);
    PH_MID(); MM(af, bg, 3);
    __builtin_amdgcn_s_setprio(0);
    if (last) { asm volatile("s_waitcnt vmcnt(0)" ::: "memory"); }
    else      { asm volatile("s_waitcnt vmcnt(4)" ::: "memory"); }
    __builtin_amdgcn_s_barrier();
    __builtin_amdgcn_sched_barrier(0);
    // ph4: compute buf1.q0; stage buf0.A-lo (tile 2i+2)
    LDB(bg, 1); LDA(af, 1, 0);
    if (!last) STAGE(A, m0, A_LDS, 0, 0, 2 * i + 2);
    PH_MID(); MM(af, bg, 0); PH_END();
    // ph5: stage buf0.A-hi
    LDA(af, 1, 1);
    if (!last) STAGE(A, m0, A_LDS, 0, 1, 2 * i + 2);
    PH_MID(); MM(af, bg, 1); PH_END();
    // ph6: stage buf1.B-lo (tile 2i+3)
    LDA(af, 1, 2);
    if (!last) STAGE(WT, n0, B_LDS, 1, 0, 2 * i + 3);
    PH_MID(); MM(af, bg, 2); PH_END();
    // ph7: close K-tile 2i+1; counted vmcnt ensures buf0 (tile 2i+2) landed
    LDA(af, 1, 3);
    if (!last) STAGE(WT, n0, B_LDS, 1, 1, 2 * i + 3);
    PH_MID(); MM(af, bg, 3);
    __builtin_amdgcn_s_setprio(0);
    asm volatile("s_waitcnt vmcnt(4)" ::: "memory");
    __builtin_amdgcn_s_barrier();
    __builtin_amdgcn_sched_barrier(0);
  }

  // epilogue: C row = m0+wr*128+i*16+(lane>>4)*4+tt, col = n0+wc*64+j*16+(lane&15)
  const int cl = lane & 15, rg = lane >> 4;
#pragma unroll
  for (int j = 0; j < 4; ++j) {
    const int cc = n0 + wc * 64 + j * 16 + cl;
    const float bias = lb[cc];
#pragma unroll
    for (int i = 0; i < 8; ++i) {
      const size_t base = (size_t)(m0 + wr * 128 + i * 16 + rg * 4) * L_SZ + cc;
#pragma unroll
      for (int tt = 0; tt < 4; ++tt) zpre[base + (size_t)tt * L_SZ] = acc[i][j][tt] + bias;
    }
  }
}

// ---------------------------------------------------------------- radix-select helper
__device__ void radix_pick(unsigned* hist, unsigned* suf, int* sh_b, unsigned* sh_above,
                           int target, int t) {
  if (t == 0) *sh_b = -1;
  unsigned p = hist[4 * t] + hist[4 * t + 1] + hist[4 * t + 2] + hist[4 * t + 3];
  suf[t] = p;
  for (int off = 1; off < 256; off <<= 1) {
    __syncthreads();
    unsigned v = (t + off < 256) ? suf[t + off] : 0u;
    __syncthreads();
    suf[t] += v;
  }
  __syncthreads();
  const unsigned shi = (t + 1 < 256) ? suf[t + 1] : 0u;
  unsigned S = shi;
  int best = -1;
#pragma unroll
  for (int i = 3; i >= 0; --i) {
    S += hist[4 * t + i];
    if (S >= (unsigned)target) { best = 4 * t + i; break; }
  }
  if (best >= 0) atomicMax(sh_b, best);
  __syncthreads();
  const int b = *sh_b;
  if ((b >> 2) == t) {
    unsigned above = shi;
    for (int i = 3; i > (b & 3); --i) above += hist[4 * t + i];
    *sh_above = above;
  }
  __syncthreads();
}

// ------------- top-C candidates per row (radix on f32 keys) + fused latent bucket counting
__global__ __launch_bounds__(256) void sae_topc(const float* __restrict__ zpre,
                                                int* __restrict__ cand_idx,
                                                int* __restrict__ cand_cnt,
                                                int* __restrict__ bk_cnt) {
  __shared__ unsigned keys[L_SZ];  // 64 KB
  __shared__ unsigned hist[1024];
  __shared__ unsigned suf[256];
  __shared__ int sh_b0, sh_b1, sh_cnt;
  __shared__ unsigned sh_above;
  const int r = blockIdx.x, t = threadIdx.x;
  const float* zr = zpre + (size_t)r * L_SZ;

  for (int i = t; i < L_SZ / 4; i += 256) {
    float4 v = ((const float4*)zr)[i];
    unsigned u0 = __float_as_uint(v.x), u1 = __float_as_uint(v.y);
    unsigned u2 = __float_as_uint(v.z), u3 = __float_as_uint(v.w);
    keys[4 * i + 0] = (u0 & 0x80000000u) ? ~u0 : (u0 | 0x80000000u);
    keys[4 * i + 1] = (u1 & 0x80000000u) ? ~u1 : (u1 | 0x80000000u);
    keys[4 * i + 2] = (u2 & 0x80000000u) ? ~u2 : (u2 | 0x80000000u);
    keys[4 * i + 3] = (u3 & 0x80000000u) ? ~u3 : (u3 | 0x80000000u);
  }
  for (int i = t; i < 1024; i += 256) hist[i] = 0;
  if (t == 0) sh_cnt = 0;
  __syncthreads();
  for (int i = t; i < L_SZ; i += 256) atomicAdd(&hist[keys[i] >> 22], 1u);
  __syncthreads();
  radix_pick(hist, suf, &sh_b0, &sh_above, C_TARGET, t);
  const int b0 = sh_b0;
  const int target2 = C_TARGET - (int)sh_above;
  __syncthreads();
  for (int i = t; i < 1024; i += 256) hist[i] = 0;
  __syncthreads();
  for (int i = t; i < L_SZ; i += 256) {
    const unsigned k = keys[i];
    if ((int)(k >> 22) == b0) atomicAdd(&hist[(k >> 12) & 1023u], 1u);
  }
  __syncthreads();
  radix_pick(hist, suf, &sh_b1, &sh_above, target2, t);
  const unsigned cutoff = (((unsigned)b0 << 10) | (unsigned)sh_b1) << 12;
  __syncthreads();
  for (int i = t; i < L_SZ; i += 256) {
    if (keys[i] >= cutoff) {
      const int s = atomicAdd(&sh_cnt, 1);
      if (s < C_CAP) {
        cand_idx[(size_t)r * C_CAP + s] = i;
        atomicAdd(&bk_cnt[i], 1);
      }
    }
  }
  __syncthreads();
  if (t == 0) cand_cnt[r] = sh_cnt < C_CAP ? sh_cnt : C_CAP;
}

// ------------------------------------------- exclusive scan over 16384 counts (1 block)
__global__ __launch_bounds__(256) void sae_scan(const int* __restrict__ counts,
                                                int* __restrict__ offsets,
                                                int* __restrict__ cursor) {
  __shared__ int part[256];
  const int t = threadIdx.x;
  int s = 0;
  for (int i = 0; i < 64; ++i) s += counts[t * 64 + i];
  part[t] = s;
  __syncthreads();
  int excl = 0;
  for (int j = 0; j < t; ++j) excl += part[j];
  int run = excl;
  for (int i = 0; i < 64; ++i) {
    const int idx = t * 64 + i;
    offsets[idx] = run;
    cursor[idx] = run;
    run += counts[idx];
  }
}

// ------------------------------------------- bucket fill: entries[pos] = (row<<8)|slot
__global__ __launch_bounds__(256) void sae_bucket_fill(const int* __restrict__ cand_idx,
                                                       const int* __restrict__ cand_cnt,
                                                       int* __restrict__ cursor,
                                                       int* __restrict__ entries) {
  const int r = blockIdx.x, t = threadIdx.x;
  if (t < cand_cnt[r]) {
    const int l = cand_idx[(size_t)r * C_CAP + t];
    const int pos = atomicAdd(&cursor[l], 1);
    entries[pos] = (r << 8) | t;
  }
}

// ------------------------------------------- latent-major exact f64 recompute
__global__ __launch_bounds__(256) void sae_refine_lm(const float* __restrict__ xs,
                                                     const float* __restrict__ WT,
                                                     const float* __restrict__ lb,
                                                     const int* __restrict__ counts,
                                                     const int* __restrict__ offsets,
                                                     const int* __restrict__ entries,
                                                     double* __restrict__ cand_val) {
  __shared__ float4 wl[D_SZ / 4];
  const int l = blockIdx.x;
  const int t = threadIdx.x, lane = t & 63, w = t >> 6;
  const float4* wc = (const float4*)(WT + (size_t)l * D_SZ);
  for (int d = t; d < D_SZ / 4; d += 256) wl[d] = wc[d];
  __syncthreads();
  const int n = counts[l], base = offsets[l];
  const double bias = (double)lb[l];
  for (int e = w; e < n; e += 4) {
    const int ent = entries[base + e];
    const int r = ent >> 8, s = ent & 255;
    const float4* xr = (const float4*)(xs + (size_t)r * D_SZ);
    double acc = 0.0;
#pragma unroll
    for (int i = 0; i < 5; ++i) {
      const float4 xv = xr[lane + 64 * i];
      const float4 wv = wl[lane + 64 * i];
      acc += (double)xv.x * (double)wv.x + (double)xv.y * (double)wv.y +
             (double)xv.z * (double)wv.z + (double)xv.w * (double)wv.w;
    }
#pragma unroll
    for (int off = 32; off > 0; off >>= 1) acc += __shfl_down(acc, off);
    if (lane == 0) cand_val[(size_t)r * C_CAP + s] = acc + bias;
  }
}

// ------------------------------------------- exact top-64 among candidates (rank by value)
__global__ __launch_bounds__(256) void sae_select64(const int* __restrict__ cand_idx,
                                                    const int* __restrict__ cand_cnt,
                                                    const double* __restrict__ cand_val,
                                                    int* __restrict__ top_idx,
                                                    float* __restrict__ top_val) {
  __shared__ double vals[C_CAP];
  __shared__ int idxs[C_CAP];
  const int r = blockIdx.x, t = threadIdx.x;
  const int nc = cand_cnt[r];
  if (t < nc) {
    vals[t] = cand_val[(size_t)r * C_CAP + t];
    idxs[t] = cand_idx[(size_t)r * C_CAP + t];
  }
  __syncthreads();
  if (t < nc) {
    const double v = vals[t];
    const int id = idxs[t];
    int rank = 0;
    for (int j = 0; j < nc; ++j) {
      const double vj = vals[j];
      if (vj > v || (vj == v && idxs[j] < id)) ++rank;
    }
    if (rank < K_TOP) {
      top_idx[(size_t)r * K_TOP + rank] = id;
      float f = (float)v;
      if (f < 0.f) f = 0.f;
      top_val[(size_t)r * K_TOP + rank] = f;
    }
  }
}

// ------------------------------------------- dense z row write (zeros + 64 values), 1 blk/row
__global__ __launch_bounds__(256) void sae_zwrite(const int* __restrict__ top_idx,
                                                  const float* __restrict__ top_val,
                                                  float* __restrict__ z) {
  __shared__ int id_s[K_TOP];
  __shared__ float v_s[K_TOP];
  const int r = blockIdx.x, t = threadIdx.x;
  if (t < K_TOP) {
    id_s[t] = top_idx[(size_t)r * K_TOP + t];
    v_s[t] = top_val[(size_t)r * K_TOP + t];
  }
  __syncthreads();
  float4* zr = (float4*)(z + (size_t)r * L_SZ);
#pragma unroll
  for (int i = 0; i < L_SZ / 4 / 256; ++i) zr[t + 256 * i] = make_float4(0.f, 0.f, 0.f, 0.f);
  __syncthreads();
  if (t < K_TOP) z[(size_t)r * L_SZ + id_s[t]] = v_s[t];
}

// ------------------------------------------- sparse decode from bf16 W_dec (halved gather)
__global__ __launch_bounds__(320) void sae_decode(const int* __restrict__ top_idx,
                                                  const float* __restrict__ top_val,
                                                  const unsigned short* __restrict__ Wdb,
                                                  const float* __restrict__ pb,
                                                  float* __restrict__ xhat) {
  __shared__ int id_s[K_TOP];
  __shared__ float v_s[K_TOP];
  const int r = blockIdx.x, t = threadIdx.x;
  if (t < K_TOP) {
    id_s[t] = top_idx[(size_t)r * K_TOP + t];
    v_s[t] = top_val[(size_t)r * K_TOP + t];
  }
  __syncthreads();
  float4 acc = ((const float4*)pb)[t];
#pragma unroll 8
  for (int k = 0; k < K_TOP; ++k) {
    const ushort4 wv = ((const ushort4*)(Wdb + (size_t)id_s[k] * D_SZ))[t];
    const float vk = v_s[k];
    acc.x += vk * bf2f(wv.x);
    acc.y += vk * bf2f(wv.y);
    acc.z += vk * bf2f(wv.z);
    acc.w += vk * bf2f(wv.w);
  }
  ((float4*)(xhat + (size_t)r * D_SZ))[t] = acc;
}

// ------------------------------------------- fallback scatter (ws too small)
__global__ void sae_scatterA(const int* __restrict__ top_idx, const float* __restrict__ top_val,
                             float* __restrict__ z) {
  const int r = blockIdx.x;
  const int t = threadIdx.x;
  const int id = top_idx[(size_t)r * K_TOP + t];
  const float v = top_val[(size_t)r * K_TOP + t];
  z[(size_t)r * L_SZ + id] = v;
}

__global__ __launch_bounds__(256) void sae_scatterB(const int* __restrict__ top_idx,
                                                    const float* __restrict__ top_val,
                                                    float* __restrict__ z) {
  __shared__ int ids[32 * K_TOP];
  __shared__ float vs[32 * K_TOP];
  const int t = threadIdx.x;
  for (int i = t; i < 32 * K_TOP; i += 256) {
    ids[i] = top_idx[(size_t)4064 * K_TOP + i];
    vs[i] = top_val[(size_t)4064 * K_TOP + i];
  }
  __syncthreads();
  float4* zz = (float4*)(z + (size_t)4064 * L_SZ);
  for (int i = t; i < 32 * L_SZ / 4; i += 256) zz[i] = make_float4(0.f, 0.f, 0.f, 0.f);
  __syncthreads();
  for (int i = t; i < 32 * K_TOP; i += 256) {
    const int rr = 4064 + i / K_TOP;
    z[(size_t)rr * L_SZ + ids[i]] = vs[i];
  }
}

extern "C" void kernel_launch(void* const* d_in, const int* in_sizes, int n_in,
                              void* d_out, int out_size, void* d_ws, size_t ws_size,
                              hipStream_t stream) {
  const float* x  = (const float*)d_in[0];
  const float* pb = (const float*)d_in[1];
  const float* We = (const float*)d_in[2];
  const float* lb = (const float*)d_in[3];
  const float* Wd = (const float*)d_in[4];

  float* zpre = (float*)d_out;
  float* z    = zpre + (size_t)B_SZ * L_SZ;
  float* xhat = z + (size_t)B_SZ * L_SZ;

  // Scratch lives inside the z output region (256 MiB), dead before z is materialized.
  char* zb = (char*)z;
  unsigned short* A_bf   = (unsigned short*)(zb);                        // 10 MiB
  unsigned short* WT_bf  = (unsigned short*)(zb + ((size_t)16 << 20));   // 40 MiB
  float*          WT_f32 = (float*)(zb + ((size_t)64 << 20));            // 80 MiB
  int*            c_idx  = (int*)(zb + ((size_t)160 << 20));             // 4 MiB
  int*            c_cnt  = (int*)(zb + ((size_t)164 << 20));             // 16 KiB
  double*         c_val  = (double*)(zb + ((size_t)168 << 20));          // 8 MiB
  float*          xs_f32 = (float*)(zb + ((size_t)176 << 20));           // 20 MiB
  int*            bk_cnt = (int*)(zb + ((size_t)200 << 20));             // 64 KiB
  int*            bk_off = (int*)(zb + ((size_t)201 << 20));             // 64 KiB
  int*            bk_cur = (int*)(zb + ((size_t)202 << 20));             // 64 KiB
  int*            bk_ent = (int*)(zb + ((size_t)208 << 20));             // 4 MiB
  unsigned short* Wd_bf  = (unsigned short*)(zb + ((size_t)212 << 20));  // 40 MiB

  const bool use_ws = ws_size >= ((size_t)4 << 20);
  int*   t_idx = use_ws ? (int*)d_ws : (int*)(zb + ((size_t)254 << 20));
  float* t_val = use_ws ? (float*)((char*)d_ws + ((size_t)2 << 20))
                        : (float*)(zb + ((size_t)255 << 20));

  sae_prep_a<<<B_SZ, 256, 0, stream>>>(x, pb, A_bf, xs_f32);
  sae_prep_w<<<dim3(L_SZ / 64, D_SZ / 64), 256, 0, stream>>>(We, WT_f32, WT_bf);
  sae_prep_wd<<<2048, 256, 0, stream>>>(Wd, Wd_bf);
  sae_gemm<<<1024, 512, 0, stream>>>(A_bf, WT_bf, lb, zpre);
  hipMemsetAsync(bk_cnt, 0, (size_t)L_SZ * sizeof(int), stream);
  sae_topc<<<B_SZ, 256, 0, stream>>>(zpre, c_idx, c_cnt, bk_cnt);
  sae_scan<<<1, 256, 0, stream>>>(bk_cnt, bk_off, bk_cur);
  sae_bucket_fill<<<B_SZ, 256, 0, stream>>>(c_idx, c_cnt, bk_cur, bk_ent);
  sae_refine_lm<<<L_SZ, 256, 0, stream>>>(xs_f32, WT_f32, lb, bk_cnt, bk_off, bk_ent, c_val);
  sae_select64<<<B_SZ, 256, 0, stream>>>(c_idx, c_cnt, c_val, t_idx, t_val);
  sae_decode<<<B_SZ, 320, 0, stream>>>(t_idx, t_val, Wd_bf, pb, xhat);
  if (use_ws) {
    sae_zwrite<<<B_SZ, 256, 0, stream>>>(t_idx, t_val, z);
  } else {
    hipMemsetAsync(z, 0, (size_t)4064 * L_SZ * sizeof(float), stream);
    sae_scatterA<<<4064, K_TOP, 0, stream>>>(t_idx, t_val, z);
    sae_scatterB<<<1, 256, 0, stream>>>(t_idx, t_val, z);
  }
}

// Round 6
// 657.607 us; speedup vs baseline: 1.8213x; 1.4122x over previous
//
#include <hip/hip_runtime.h>
#include <hip/hip_bf16.h>
#include <stdint.h>

#define B_SZ 4096
#define D_SZ 1280
#define L_SZ 16384
#define K_TOP 64
#define C_CAP 192
#define BAND 0.07f

typedef __attribute__((ext_vector_type(8))) short s16x8;
typedef __attribute__((ext_vector_type(4))) float f32x4;

#define GLOAD_LDS16(gp, lp)                                                          \
  __builtin_amdgcn_global_load_lds((const __attribute__((address_space(1))) void*)(gp), \
                                   (__attribute__((address_space(3))) void*)(lp), 16, 0, 0)

static __device__ __forceinline__ unsigned short f2bf(float f) {
  __hip_bfloat16 h = __float2bfloat16(f);
  return *reinterpret_cast<unsigned short*>(&h);
}
static __device__ __forceinline__ float bf2f(unsigned short u) {
  return __uint_as_float((unsigned)u << 16);
}
// order-preserving f32 <-> u32 key
static __device__ __forceinline__ unsigned mkkey(float f) {
  const unsigned u = __float_as_uint(f);
  return (u & 0x80000000u) ? ~u : (u | 0x80000000u);
}
static __device__ __forceinline__ float unkey(unsigned k) {
  const unsigned u = (k & 0x80000000u) ? (k & 0x7fffffffu) : ~k;
  return __uint_as_float(u);
}

// ---------------- fused prep: W_encT(f32+bf16) | A=bf16(x-pb),xs=f32(x-pb) | Wd bf16 | zero bk_cnt
__global__ __launch_bounds__(256) void sae_prep(const float* __restrict__ x,
                                                const float* __restrict__ pb,
                                                const float* __restrict__ We,
                                                const float* __restrict__ Wd,
                                                unsigned short* __restrict__ A,
                                                float* __restrict__ xs,
                                                float* __restrict__ WT,
                                                unsigned short* __restrict__ WbT,
                                                unsigned short* __restrict__ Wdb,
                                                int* __restrict__ bk_cnt) {
  const int b = blockIdx.x, t = threadIdx.x;
  if (b < 5120) {  // W_enc transpose tiles: 256 l-tiles x 20 d-tiles
    __shared__ float tile[64][65];
    const int l0 = (b & 255) * 64, d0 = (b >> 8) * 64;
    const int c = t & 63, rg = t >> 6;
#pragma unroll
    for (int i = 0; i < 16; ++i) {
      const int row = i * 4 + rg;
      tile[row][c] = We[(size_t)(d0 + row) * L_SZ + l0 + c];
    }
    __syncthreads();
#pragma unroll
    for (int i = 0; i < 16; ++i) {
      const int row = i * 4 + rg;
      const float v = tile[c][row];
      const size_t o = (size_t)(l0 + row) * D_SZ + d0 + c;
      WT[o] = v;
      WbT[o] = f2bf(v);
    }
  } else if (b < 5120 + 4096) {  // x - pb
    const int r = b - 5120;
    const float* xr = x + (size_t)r * D_SZ;
    unsigned short* ar = A + (size_t)r * D_SZ;
    float* sr = xs + (size_t)r * D_SZ;
    for (int d = t; d < D_SZ; d += 256) {
      const float v = xr[d] - pb[d];
      ar[d] = f2bf(v);
      sr[d] = v;
    }
  } else if (b < 5120 + 4096 + 2048) {  // W_dec -> bf16
    const int n4 = L_SZ * D_SZ / 4;
    for (int i = (b - 9216) * 256 + t; i < n4; i += 2048 * 256) {
      const float4 v = ((const float4*)Wd)[i];
      ushort4 o;
      o.x = f2bf(v.x); o.y = f2bf(v.y); o.z = f2bf(v.z); o.w = f2bf(v.w);
      ((ushort4*)Wdb)[i] = o;
    }
  } else {  // 64 blocks: zero bucket counts
    bk_cnt[(b - 11264) * 256 + t] = 0;
  }
}

// ---------------------------------------------------------------- encode GEMM, 256x256 8-phase
#define SWZ(lin) ((lin) ^ ((((lin) >> 9) & 7) << 4))
#define A_LDS 0
#define B_LDS 65536
#define KBYTES (D_SZ * 2)

#define PH_MID()                                          \
  __builtin_amdgcn_s_barrier();                           \
  asm volatile("s_waitcnt lgkmcnt(0)" ::: "memory");      \
  __builtin_amdgcn_sched_barrier(0);                      \
  __builtin_amdgcn_s_setprio(1)

#define PH_END()                                          \
  __builtin_amdgcn_s_setprio(0);                          \
  __builtin_amdgcn_s_barrier();                           \
  __builtin_amdgcn_sched_barrier(0)

__global__ __launch_bounds__(512, 2) void sae_gemm(const unsigned short* __restrict__ A,
                                                   const unsigned short* __restrict__ WT,
                                                   const float* __restrict__ lb,
                                                   float* __restrict__ zpre) {
  __shared__ short lds[65536];  // 128 KiB
  char* ldsc = (char*)lds;
  const int t = threadIdx.x, lane = t & 63, w = t >> 6;
  const int wr = w >> 2, wc = w & 3, w2 = w * 2;

  const int bid = blockIdx.x;
  const int xcd = bid & 7, i2 = bid >> 3;
  const int b2 = i2 >> 4, inner = i2 & 15;
  const int mt = (b2 & 3) * 4 + (inner & 3);
  const int nt = xcd * 8 + (b2 >> 2) * 4 + (inner >> 2);
  const int m0 = mt * 256, n0 = nt * 256;

  f32x4 acc[8][4] = {};

  auto STAGE = [&](const unsigned short* op, int rowbase, int ldsop, int buf, int half, int tile) {
#pragma unroll
    for (int s = 0; s < 2; ++s) {
      const int o = (w2 + s) * 1024 + lane * 16;
      const int r = o >> 7;
      const int cb = (o & 127) ^ (((o >> 9) & 7) << 4);
      const char* g = (const char*)op + (size_t)(rowbase + half * 128 + r) * KBYTES +
                      tile * 128 + cb;
      char* l = ldsc + ldsop + buf * 32768 + half * 16384 + (w2 + s) * 1024;
      GLOAD_LDS16(g, l);
    }
  };
  auto LDA = [&](s16x8* af, int buf, int q) {
#pragma unroll
    for (int i = 0; i < 2; ++i)
#pragma unroll
      for (int kk = 0; kk < 2; ++kk) {
        const int r = (q * 2 + i) * 16 + (lane & 15);
        int lin = r * 128 + kk * 64 + ((lane >> 4) * 16);
        lin = SWZ(lin);
        af[i * 2 + kk] = *(const s16x8*)(ldsc + A_LDS + buf * 32768 + wr * 16384 + lin);
      }
  };
  auto LDB = [&](s16x8* bg, int buf) {
#pragma unroll
    for (int j = 0; j < 4; ++j)
#pragma unroll
      for (int kk = 0; kk < 2; ++kk) {
        const int nloc = wc * 64 + j * 16 + (lane & 15);
        const int half = nloc >> 7, r = nloc & 127;
        int lin = r * 128 + kk * 64 + ((lane >> 4) * 16);
        lin = SWZ(lin);
        bg[j * 2 + kk] = *(const s16x8*)(ldsc + B_LDS + buf * 32768 + half * 16384 + lin);
      }
  };
  auto MM = [&](s16x8* af, s16x8* bg, int q) {
#pragma unroll
    for (int i = 0; i < 2; ++i)
#pragma unroll
      for (int j = 0; j < 4; ++j)
#pragma unroll
        for (int kk = 0; kk < 2; ++kk)
          acc[q * 2 + i][j] =
              __builtin_amdgcn_mfma_f32_16x16x32_bf16(af[i * 2 + kk], bg[j * 2 + kk],
                                                      acc[q * 2 + i][j], 0, 0, 0);
  };

  STAGE(WT, n0, B_LDS, 0, 0, 0); STAGE(WT, n0, B_LDS, 0, 1, 0);
  STAGE(A, m0, A_LDS, 0, 0, 0);  STAGE(A, m0, A_LDS, 0, 1, 0);
  STAGE(WT, n0, B_LDS, 1, 0, 1); STAGE(WT, n0, B_LDS, 1, 1, 1);
  asm volatile("s_waitcnt vmcnt(4)" ::: "memory");
  __builtin_amdgcn_s_barrier();
  __builtin_amdgcn_sched_barrier(0);

  const int NI = D_SZ / 128;
  for (int i = 0; i < NI; ++i) {
    const bool last = (i == NI - 1);
    s16x8 af[4], bg[8];
    LDB(bg, 0); LDA(af, 0, 0);
    STAGE(A, m0, A_LDS, 1, 0, 2 * i + 1); STAGE(A, m0, A_LDS, 1, 1, 2 * i + 1);
    PH_MID(); MM(af, bg, 0); PH_END();
    LDA(af, 0, 1);
    if (!last) STAGE(WT, n0, B_LDS, 0, 0, 2 * i + 2);
    PH_MID(); MM(af, bg, 1); PH_END();
    LDA(af, 0, 2);
    if (!last) STAGE(WT, n0, B_LDS, 0, 1, 2 * i + 2);
    PH_MID(); MM(af, bg, 2); PH_END();
    LDA(af, 0, 3);
    PH_MID(); MM(af, bg, 3);
    __builtin_amdgcn_s_setprio(0);
    if (last) { asm volatile("s_waitcnt vmcnt(0)" ::: "memory"); }
    else      { asm volatile("s_waitcnt vmcnt(4)" ::: "memory"); }
    __builtin_amdgcn_s_barrier();
    __builtin_amdgcn_sched_barrier(0);
    LDB(bg, 1); LDA(af, 1, 0);
    if (!last) STAGE(A, m0, A_LDS, 0, 0, 2 * i + 2);
    PH_MID(); MM(af, bg, 0); PH_END();
    LDA(af, 1, 1);
    if (!last) STAGE(A, m0, A_LDS, 0, 1, 2 * i + 2);
    PH_MID(); MM(af, bg, 1); PH_END();
    LDA(af, 1, 2);
    if (!last) STAGE(WT, n0, B_LDS, 1, 0, 2 * i + 3);
    PH_MID(); MM(af, bg, 2); PH_END();
    LDA(af, 1, 3);
    if (!last) STAGE(WT, n0, B_LDS, 1, 1, 2 * i + 3);
    PH_MID(); MM(af, bg, 3);
    __builtin_amdgcn_s_setprio(0);
    asm volatile("s_waitcnt vmcnt(4)" ::: "memory");
    __builtin_amdgcn_s_barrier();
    __builtin_amdgcn_sched_barrier(0);
  }

  const int cl = lane & 15, rg = lane >> 4;
#pragma unroll
  for (int j = 0; j < 4; ++j) {
    const int cc = n0 + wc * 64 + j * 16 + cl;
    const float bias = lb[cc];
#pragma unroll
    for (int i = 0; i < 8; ++i) {
      const size_t base = (size_t)(m0 + wr * 128 + i * 16 + rg * 4) * L_SZ + cc;
#pragma unroll
      for (int tt = 0; tt < 4; ++tt) zpre[base + (size_t)tt * L_SZ] = acc[i][j][tt] + bias;
    }
  }
}

// ---------------------------------------------------------------- radix-select helper
__device__ void radix_pick(unsigned* hist, unsigned* suf, int* sh_b, unsigned* sh_above,
                           int target, int t) {
  if (t == 0) *sh_b = -1;
  unsigned p = hist[4 * t] + hist[4 * t + 1] + hist[4 * t + 2] + hist[4 * t + 3];
  suf[t] = p;
  for (int off = 1; off < 256; off <<= 1) {
    __syncthreads();
    unsigned v = (t + off < 256) ? suf[t + off] : 0u;
    __syncthreads();
    suf[t] += v;
  }
  __syncthreads();
  const unsigned shi = (t + 1 < 256) ? suf[t + 1] : 0u;
  unsigned S = shi;
  int best = -1;
#pragma unroll
  for (int i = 3; i >= 0; --i) {
    S += hist[4 * t + i];
    if (S >= (unsigned)target) { best = 4 * t + i; break; }
  }
  if (best >= 0) atomicMax(sh_b, best);
  __syncthreads();
  const int b = *sh_b;
  if ((b >> 2) == t) {
    unsigned above = shi;
    for (int i = 3; i > (b & 3); --i) above += hist[4 * t + i];
    *sh_above = above;
  }
  __syncthreads();
}

// -------- value-based band selection around rank-64.
// Two-level radix on target 64 -> key(v64) in [v64lb_key, v64lb_key+4095].
// Collect ALL vals >= unkey(v64lb)-BAND: hi (> unkey(v64ub)+BAND) = provably exact top-64;
// rest = band (exact f64 recompute decides). Watertight under |zpre err| <= BAND/2.
__global__ __launch_bounds__(256) void sae_topc(const float* __restrict__ zpre,
                                                int* __restrict__ bk_cnt,
                                                int* __restrict__ band_lat,
                                                float* __restrict__ band_fval,
                                                int* __restrict__ n_hi,
                                                int* __restrict__ n_band,
                                                int* __restrict__ t_idx,
                                                float* __restrict__ t_val) {
  __shared__ unsigned hist[1024];
  __shared__ unsigned suf[256];
  __shared__ int sh_b0, sh_b1, sh_nhi, sh_nband;
  __shared__ unsigned sh_above;
  const int r = blockIdx.x, t = threadIdx.x;
  const float4* zr4 = (const float4*)(zpre + (size_t)r * L_SZ);

  for (int i = t; i < 1024; i += 256) hist[i] = 0;
  if (t == 0) { sh_nhi = 0; sh_nband = 0; }
  __syncthreads();
  for (int i = t; i < L_SZ / 4; i += 256) {
    const float4 v = zr4[i];
    atomicAdd(&hist[mkkey(v.x) >> 22], 1u);
    atomicAdd(&hist[mkkey(v.y) >> 22], 1u);
    atomicAdd(&hist[mkkey(v.z) >> 22], 1u);
    atomicAdd(&hist[mkkey(v.w) >> 22], 1u);
  }
  __syncthreads();
  radix_pick(hist, suf, &sh_b0, &sh_above, K_TOP, t);
  const int b0 = sh_b0;
  const int target2 = K_TOP - (int)sh_above;
  __syncthreads();
  for (int i = t; i < 1024; i += 256) hist[i] = 0;
  __syncthreads();
  for (int i = t; i < L_SZ / 4; i += 256) {
    const float4 v = zr4[i];
    const float va[4] = {v.x, v.y, v.z, v.w};
#pragma unroll
    for (int q = 0; q < 4; ++q) {
      const unsigned k = mkkey(va[q]);
      if ((int)(k >> 22) == b0) atomicAdd(&hist[(k >> 12) & 1023u], 1u);
    }
  }
  __syncthreads();
  radix_pick(hist, suf, &sh_b1, &sh_above, target2, t);
  const unsigned v64lb_key = (((unsigned)b0 << 10) | (unsigned)sh_b1) << 12;
  const float lo_f = unkey(v64lb_key) - BAND;           // collect threshold (conservative)
  const float hi_f = unkey(v64lb_key + 4095u) + BAND;   // provably-in threshold (conservative)
  __syncthreads();
  for (int i = t; i < L_SZ / 4; i += 256) {
    const float4 v = zr4[i];
    const float va[4] = {v.x, v.y, v.z, v.w};
#pragma unroll
    for (int q = 0; q < 4; ++q) {
      const float val = va[q];
      if (val >= lo_f) {
        const int l = 4 * i + q;
        if (val > hi_f) {
          const int p = atomicAdd(&sh_nhi, 1);
          if (p < K_TOP) {
            t_idx[(size_t)r * K_TOP + p] = l;
            t_val[(size_t)r * K_TOP + p] = fmaxf(val, 0.f);
          }
        } else {
          const int p = atomicAdd(&sh_nband, 1);
          if (p < C_CAP) {
            band_lat[(r << 8) + p] = l;
            band_fval[(r << 8) + p] = val;
            atomicAdd(&bk_cnt[l], 1);
          }
        }
      }
    }
  }
  __syncthreads();
  if (t == 0) {
    n_hi[r] = sh_nhi < K_TOP ? sh_nhi : K_TOP;
    n_band[r] = sh_nband < C_CAP ? sh_nband : C_CAP;
  }
}

// ------------------------------------------- exclusive scan over 16384 counts (1 block)
__global__ __launch_bounds__(256) void sae_scan(const int* __restrict__ counts,
                                                int* __restrict__ offsets,
                                                int* __restrict__ cursor) {
  __shared__ int part[256];
  const int t = threadIdx.x;
  int s = 0;
  for (int i = 0; i < 64; ++i) s += counts[t * 64 + i];
  part[t] = s;
  __syncthreads();
  int excl = 0;
  for (int j = 0; j < t; ++j) excl += part[j];
  int run = excl;
  for (int i = 0; i < 64; ++i) {
    const int idx = t * 64 + i;
    offsets[idx] = run;
    cursor[idx] = run;
    run += counts[idx];
  }
}

// ------------------------------------------- bucket fill: entries[pos] = (row<<8)|slot
__global__ __launch_bounds__(192) void sae_bucket_fill(const int* __restrict__ band_lat,
                                                       const int* __restrict__ n_band,
                                                       int* __restrict__ cursor,
                                                       int* __restrict__ entries) {
  const int r = blockIdx.x, t = threadIdx.x;
  if (t < n_band[r]) {
    const int l = band_lat[(r << 8) + t];
    const int pos = atomicAdd(&cursor[l], 1);
    entries[pos] = (r << 8) | t;
  }
}

// ------------------------------------------- latent-major exact f64 recompute (band only)
__global__ __launch_bounds__(256) void sae_refine_lm(const float* __restrict__ xs,
                                                     const float* __restrict__ WT,
                                                     const float* __restrict__ lb,
                                                     const int* __restrict__ counts,
                                                     const int* __restrict__ offsets,
                                                     const int* __restrict__ entries,
                                                     double* __restrict__ band_eval) {
  __shared__ float4 wl[D_SZ / 4];
  const int l = blockIdx.x;
  const int t = threadIdx.x, lane = t & 63, w = t >> 6;
  const int n = counts[l];
  if (n == 0) return;
  const float4* wc = (const float4*)(WT + (size_t)l * D_SZ);
  for (int d = t; d < D_SZ / 4; d += 256) wl[d] = wc[d];
  __syncthreads();
  const int base = offsets[l];
  const double bias = (double)lb[l];
  for (int e = w; e < n; e += 4) {
    const int ent = entries[base + e];
    const int rr = ent >> 8;
    const float4* xr = (const float4*)(xs + (size_t)rr * D_SZ);
    double acc = 0.0;
#pragma unroll
    for (int i = 0; i < 5; ++i) {
      const float4 xv = xr[lane + 64 * i];
      const float4 wv = wl[lane + 64 * i];
      acc += (double)xv.x * (double)wv.x + (double)xv.y * (double)wv.y +
             (double)xv.z * (double)wv.z + (double)xv.w * (double)wv.w;
    }
#pragma unroll
    for (int off = 32; off > 0; off >>= 1) acc += __shfl_down(acc, off);
    if (lane == 0) band_eval[ent] = acc + bias;
  }
}

// -------- finish: band exact-rank fills t slots [nh,64); decode xhat; optionally write z row.
// Scratch must NOT alias z when WRITE_Z (enforced by host layout).
template <bool WRITE_Z>
__global__ __launch_bounds__(320) void sae_finish(const int* __restrict__ n_hi,
                                                  const int* __restrict__ n_band,
                                                  const int* __restrict__ band_lat,
                                                  const float* __restrict__ band_fval,
                                                  const double* __restrict__ band_eval,
                                                  int* __restrict__ t_idx,
                                                  float* __restrict__ t_val,
                                                  const unsigned short* __restrict__ Wdb,
                                                  const float* __restrict__ pb,
                                                  float* __restrict__ z,
                                                  float* __restrict__ xhat) {
  __shared__ int bl[C_CAP];
  __shared__ float bf[C_CAP];
  __shared__ double be[C_CAP];
  __shared__ int ids[K_TOP];
  __shared__ float vs[K_TOP];
  const int r = blockIdx.x, t = threadIdx.x;
  const int nh = n_hi[r], nb = n_band[r];
  if (t < nb) {
    bl[t] = band_lat[(r << 8) + t];
    bf[t] = band_fval[(r << 8) + t];
    be[t] = band_eval[(r << 8) + t];
  }
  if (t < nh) {
    ids[t] = t_idx[(size_t)r * K_TOP + t];
    vs[t] = t_val[(size_t)r * K_TOP + t];
  }
  __syncthreads();
  const int need = K_TOP - nh;
  if (t < nb) {
    const double ev = be[t];
    const int l = bl[t];
    int rank = 0;
    for (int j = 0; j < nb; ++j) {
      const double e2 = be[j];
      if (e2 > ev || (e2 == ev && bl[j] < l)) ++rank;
    }
    if (rank < need) {
      const float fv = fmaxf(bf[t], 0.f);
      ids[nh + rank] = l;
      vs[nh + rank] = fv;
      t_idx[(size_t)r * K_TOP + nh + rank] = l;
      t_val[(size_t)r * K_TOP + nh + rank] = fv;
    }
  }
  __syncthreads();
  // decode: 320 threads x float4 = 1280 = D
  float4 acc = ((const float4*)pb)[t];
#pragma unroll 8
  for (int k = 0; k < K_TOP; ++k) {
    const ushort4 wv = ((const ushort4*)(Wdb + (size_t)ids[k] * D_SZ))[t];
    const float vk = vs[k];
    acc.x += vk * bf2f(wv.x);
    acc.y += vk * bf2f(wv.y);
    acc.z += vk * bf2f(wv.z);
    acc.w += vk * bf2f(wv.w);
  }
  ((float4*)(xhat + (size_t)r * D_SZ))[t] = acc;
  if (WRITE_Z) {
    float4* zr = (float4*)(z + (size_t)r * L_SZ);
    for (int i = t; i < L_SZ / 4; i += 320) zr[i] = make_float4(0.f, 0.f, 0.f, 0.f);
    __syncthreads();
    if (t < K_TOP) z[(size_t)r * L_SZ + ids[t]] = vs[t];
  }
}

// ------------------------------------------- fallback scatter (ws too small)
__global__ void sae_scatterA(const int* __restrict__ top_idx, const float* __restrict__ top_val,
                             float* __restrict__ z) {
  const int r = blockIdx.x;
  const int t = threadIdx.x;
  const int id = top_idx[(size_t)r * K_TOP + t];
  const float v = top_val[(size_t)r * K_TOP + t];
  z[(size_t)r * L_SZ + id] = v;
}

__global__ __launch_bounds__(256) void sae_scatterB(const int* __restrict__ top_idx,
                                                    const float* __restrict__ top_val,
                                                    float* __restrict__ z) {
  __shared__ int ids[32 * K_TOP];
  __shared__ float vs[32 * K_TOP];
  const int t = threadIdx.x;
  for (int i = t; i < 32 * K_TOP; i += 256) {
    ids[i] = top_idx[(size_t)4064 * K_TOP + i];
    vs[i] = top_val[(size_t)4064 * K_TOP + i];
  }
  __syncthreads();
  float4* zz = (float4*)(z + (size_t)4064 * L_SZ);
  for (int i = t; i < 32 * L_SZ / 4; i += 256) zz[i] = make_float4(0.f, 0.f, 0.f, 0.f);
  __syncthreads();
  for (int i = t; i < 32 * K_TOP; i += 256) {
    const int rr = 4064 + i / K_TOP;
    z[(size_t)rr * L_SZ + ids[i]] = vs[i];
  }
}

extern "C" void kernel_launch(void* const* d_in, const int* in_sizes, int n_in,
                              void* d_out, int out_size, void* d_ws, size_t ws_size,
                              hipStream_t stream) {
  const float* x  = (const float*)d_in[0];
  const float* pb = (const float*)d_in[1];
  const float* We = (const float*)d_in[2];
  const float* lb = (const float*)d_in[3];
  const float* Wd = (const float*)d_in[4];

  float* zpre = (float*)d_out;
  float* z    = zpre + (size_t)B_SZ * L_SZ;
  float* xhat = z + (size_t)B_SZ * L_SZ;

  // Scratch preferentially in d_ws (no aliasing with outputs). Fallback: inside z region
  // (dead until final phase) with the R4-proven ordering (finish does NOT write z there).
  const bool use_ws = ws_size >= ((size_t)234 << 20);
  char* sb = use_ws ? (char*)d_ws : (char*)z;

  unsigned short* A_bf   = (unsigned short*)(sb);                        // 10 MiB
  unsigned short* WT_bf  = (unsigned short*)(sb + ((size_t)16 << 20));   // 40 MiB
  float*          WT_f32 = (float*)(sb + ((size_t)64 << 20));            // 80 MiB
  float*          xs_f32 = (float*)(sb + ((size_t)144 << 20));           // 20 MiB
  int*            b_lat  = (int*)(sb + ((size_t)164 << 20));             // 4 MiB
  float*          b_fval = (float*)(sb + ((size_t)168 << 20));           // 4 MiB
  double*         b_eval = (double*)(sb + ((size_t)172 << 20));          // 8 MiB
  int*            bk_cnt = (int*)(sb + ((size_t)180 << 20));             // 64 KiB
  int*            bk_off = (int*)(sb + ((size_t)181 << 20));             // 64 KiB
  int*            bk_cur = (int*)(sb + ((size_t)182 << 20));             // 64 KiB
  int*            bk_ent = (int*)(sb + ((size_t)184 << 20));             // 3 MiB
  unsigned short* Wd_bf  = (unsigned short*)(sb + ((size_t)188 << 20));  // 40 MiB
  int*            nhi_g  = (int*)(sb + ((size_t)228 << 20));             // 16 KiB
  int*            nbd_g  = (int*)(sb + ((size_t)229 << 20));             // 16 KiB
  int*   t_idx = use_ws ? (int*)(sb + ((size_t)230 << 20))
                        : (int*)((char*)z + ((size_t)254 << 20));        // 1 MiB
  float* t_val = use_ws ? (float*)(sb + ((size_t)232 << 20))
                        : (float*)((char*)z + ((size_t)255 << 20));      // 1 MiB

  sae_prep<<<11328, 256, 0, stream>>>(x, pb, We, Wd, A_bf, xs_f32, WT_f32, WT_bf, Wd_bf, bk_cnt);
  sae_gemm<<<1024, 512, 0, stream>>>(A_bf, WT_bf, lb, zpre);
  sae_topc<<<B_SZ, 256, 0, stream>>>(zpre, bk_cnt, b_lat, b_fval, nhi_g, nbd_g, t_idx, t_val);
  sae_scan<<<1, 256, 0, stream>>>(bk_cnt, bk_off, bk_cur);
  sae_bucket_fill<<<B_SZ, 192, 0, stream>>>(b_lat, nbd_g, bk_cur, bk_ent);
  sae_refine_lm<<<L_SZ, 256, 0, stream>>>(xs_f32, WT_f32, lb, bk_cnt, bk_off, bk_ent, b_eval);
  if (use_ws) {
    sae_finish<true><<<B_SZ, 320, 0, stream>>>(nhi_g, nbd_g, b_lat, b_fval, b_eval, t_idx, t_val,
                                               Wd_bf, pb, z, xhat);
  } else {
    sae_finish<false><<<B_SZ, 320, 0, stream>>>(nhi_g, nbd_g, b_lat, b_fval, b_eval, t_idx, t_val,
                                                Wd_bf, pb, z, xhat);
    hipMemsetAsync(z, 0, (size_t)4064 * L_SZ * sizeof(float), stream);
    sae_scatterA<<<4064, K_TOP, 0, stream>>>(t_idx, t_val, z);
    sae_scatterB<<<1, 256, 0, stream>>>(t_idx, t_val, z);
  }
}